// Round 12
// baseline (545.081 us; speedup 1.0000x reference)
//
#include <hip/hip_runtime.h>

typedef unsigned short u16;
typedef float f4 __attribute__((ext_vector_type(4)));
typedef float f32x4 __attribute__((ext_vector_type(4)));
typedef short bf16x8 __attribute__((ext_vector_type(8)));
typedef u16 u16x8 __attribute__((ext_vector_type(8)));
typedef u16 u16x4 __attribute__((ext_vector_type(4)));

__device__ __forceinline__ u16 f2bf(float f){
  unsigned u = __float_as_uint(f);
  u = (u + 0x7FFFu + ((u>>16)&1u)) >> 16;
  return (u16)u;
}
__device__ __forceinline__ float bf2f(u16 u){
  return __uint_as_float(((unsigned)u)<<16);
}
// tanh-form GELU: max |dev| vs exact erf-GELU ~1e-3 (threshold is 0.108).
__device__ __forceinline__ float gelu_f(float x){
  float y = 1.5957691216057308f*(x + 0.044715f*x*x*x);
  y = fminf(y, 30.0f);
  float t = __expf(y);
  float r = __builtin_amdgcn_rcpf(t + 1.0f);
  return 0.5f*x*(1.0f + (t - 1.0f)*r);
}

// async global->LDS 16B (LDS dest is wave-uniform base + lane*16)
typedef __attribute__((address_space(1))) const unsigned int as1_cuint;
typedef __attribute__((address_space(3))) unsigned int as3_uint;
__device__ __forceinline__ void gload_lds16(const void* g, void* l){
  __builtin_amdgcn_global_load_lds((as1_cuint*)g, (as3_uint*)l, 16, 0, 0);
}

// chunk -> swizzled global col offset (u16), swz(r) = (r&3)^((r>>2)&3).
// Same involution applied on the read side -> 8-way bank conflict becomes 2-way.
__device__ __forceinline__ int gswz(int c){
  const int r = c >> 2;
  return (((c & 3) ^ ((r & 3) ^ ((r >> 2) & 3))) * 8);
}

// ---------------------------------------------------------------------------
// feat NCHW fp32 -> NHWC bf16  ([4][256][256][64])
// ---------------------------------------------------------------------------
__global__ __launch_bounds__(256) void to_nhwc(
    const float* __restrict__ F, u16* __restrict__ O)
{
  __shared__ float tile[64][65];
  const int t = threadIdx.x, b = blockIdx.y;
  const long px0 = (long)blockIdx.x*64;
  const float* Fb = F + (long)b*64*65536;
  #pragma unroll
  for (int i = 0; i < 4; ++i){
    const int ch = (t>>4) + i*16;
    const int pxo = (t&15)*4;
    f4 v = *(const f4*)&Fb[(long)ch*65536 + px0 + pxo];
    tile[ch][pxo]=v[0]; tile[ch][pxo+1]=v[1]; tile[ch][pxo+2]=v[2]; tile[ch][pxo+3]=v[3];
  }
  __syncthreads();
  const int px = t & 63, ch0 = (t>>6)*16;
  u16x8 o0, o1;
  #pragma unroll
  for (int j = 0; j < 8; ++j){ o0[j]=f2bf(tile[ch0+j][px]); o1[j]=f2bf(tile[ch0+8+j][px]); }
  u16* Ob = O + ((long)b*65536 + px0 + px)*64 + ch0;
  *(u16x8*)Ob = o0; *(u16x8*)(Ob+8) = o1;
}

// ---------------------------------------------------------------------------
// conv weights -> Wt2[((dy*3+dx)*2+kc)*192 + n][32]  (fragment-contiguous bf16)
// ---------------------------------------------------------------------------
__global__ __launch_bounds__(256) void wt_prep(
    const float* __restrict__ we, const float* __restrict__ wk,
    const float* __restrict__ wv, u16* __restrict__ Wt2)
{
  const int i = blockIdx.x*256 + threadIdx.x;   // 110592 total
  const int cio = i & 31;
  const int t1 = i >> 5;
  const int n  = t1 % 192;
  const int t2 = t1 / 192;
  const int kc = t2 & 1, p = t2 >> 1;
  const int dy = p/3, dx = p - dy*3;
  const int ci = kc*32 + cio;
  const float* W = (n < 64) ? we : (n < 128) ? wk : wv;
  const int co = n & 63;
  Wt2[i] = f2bf(W[((co*64 + ci)*3 + dy)*3 + dx]);
}

// ---------------------------------------------------------------------------
// MFMA implicit-GEMM conv (512 thr, 2 blocks/CU, two-phase LDS epilogue).
// ---------------------------------------------------------------------------
__global__ __launch_bounds__(512,2) void conv_mfma(
    const u16* __restrict__ X, const u16* __restrict__ Wt2,
    const float* __restrict__ be, const float* __restrict__ bk, const float* __restrict__ bv,
    u16* __restrict__ Aq, u16* __restrict__ Ak, u16* __restrict__ Vl)
{
  __shared__ __align__(16) u16 smem[24576];   // 48KB: halo / epilogue reuse
  const int t = threadIdx.x, lane = t & 63, wvi = t >> 6;
  const int bx = blockIdx.x, by = blockIdx.y, b = blockIdx.z;
  const int x0 = bx*16, y0 = by*8;
  const u16* Xb = X + (long)b*4194304;

  #pragma unroll
  for (int j = 0; j < 3; ++j){
    const int id = t + j*512;
    if (id < 1440){
      const int row = id / 144, rem = id - row*144, col = rem >> 3, ck = rem & 7;
      const int y = y0 - 1 + row, x = x0 - 1 + col;
      int4 v = {0,0,0,0};
      if ((unsigned)y < 256u && (unsigned)x < 256u)
        v = *(const int4*)(Xb + ((long)y*256 + x)*64 + ck*8);
      *(int4*)&smem[((row*18 + col)*8 + (ck ^ (col&7)))*8] = v;
    }
  }
  __syncthreads();

  const int wm4 = (wvi>>2)*4;
  const int wn  = (wvi&3)*48;
  const int fr = lane & 15, fo = lane >> 4;
  f32x4 acc[4][3] = {};

  #pragma unroll
  for (int dy = 0; dy < 3; ++dy)
  #pragma unroll
  for (int dx = 0; dx < 3; ++dx){
    const int p = dy*3 + dx;
    #pragma unroll
    for (int kc = 0; kc < 2; ++kc){
      bf16x8 af[4], bfv[3];
      const u16* wp = Wt2 + ((long)(p*2 + kc)*192 + wn + fr)*32 + fo*8;
      #pragma unroll
      for (int ni = 0; ni < 3; ++ni)
        bfv[ni] = *(const bf16x8*)(wp + ni*16*32);
      #pragma unroll
      for (int mi = 0; mi < 4; ++mi){
        const int row = wm4 + mi + dy;
        const int col = fr + dx;
        af[mi] = *(const bf16x8*)&smem[((row*18 + col)*8 + ((kc*4+fo) ^ (col&7)))*8];
      }
      #pragma unroll
      for (int mi = 0; mi < 4; ++mi)
        #pragma unroll
        for (int ni = 0; ni < 3; ++ni)
          acc[mi][ni] = __builtin_amdgcn_mfma_f32_16x16x32_bf16(af[mi], bfv[ni], acc[mi][ni], 0, 0, 0);
    }
  }
  __syncthreads();

  // phase 1: bias+GELU, frags -> LDS
  const int c0 = fo*4;
  const int lloc = c0 >> 3, kw0 = c0 & 7;
  #pragma unroll
  for (int ni = 0; ni < 3; ++ni){
    const int n = wn + ni*16 + fr;
    const int mat = n >> 6, co = n & 63;
    const float bias = (mat==0) ? be[co] : (mat==1) ? bk[co] : bv[co];
    #pragma unroll
    for (int mi = 0; mi < 4; ++mi){
      const int r = wm4 + mi;
      u16x4 o;
      #pragma unroll
      for (int rg = 0; rg < 4; ++rg) o[rg] = f2bf(gelu_f(acc[mi][ni][rg] + bias));
      const int e = ((mat*2 + lloc)*64 + co)*64 + ((r*8 + kw0) ^ ((co&7)<<3));
      *(u16x4*)&smem[e] = o;
    }
  }
  __syncthreads();

  // phase 2: six contiguous 8KB rows, 16B/lane coalesced
  const int l_lo = by*32 + bx*2;
  const int co_r = t >> 3, sw = (t&7) ^ (co_r&7);
  const int eoff = co_r*64 + sw*8;
  #pragma unroll
  for (int i = 0; i < 6; ++i){
    const int mat = i >> 1, ll = i & 1;
    u16x8 v = *(const u16x8*)&smem[(mat*2 + ll)*4096 + eoff];
    u16* dst = (mat==0 ? Aq : mat==1 ? Ak : Vl)
             + ((long)b*1024 + l_lo + ll)*4096 + t*8;
    *(u16x8*)dst = v;
  }
}

// ---------------------------------------------------------------------------
// V transpose: [b][l=1024][ck=4096] -> [b][ck][l]
// ---------------------------------------------------------------------------
__global__ __launch_bounds__(256) void v_tr(
    const u16* __restrict__ S, u16* __restrict__ D)
{
  __shared__ u16 tl[64][72];
  const int t = threadIdx.x, b = blockIdx.z;
  const int ck0 = blockIdx.x*64, l0 = blockIdx.y*64;
  const u16* Sb = S + (long)b*4194304;
  u16* Db = D + (long)b*4194304;
  #pragma unroll
  for (int j = 0; j < 2; ++j){
    const int li = (t>>3) + j*32, cko = (t&7)*8;
    *(u16x8*)&tl[li][cko] = *(const u16x8*)(Sb + (long)(l0+li)*4096 + ck0 + cko);
  }
  __syncthreads();
  #pragma unroll
  for (int j = 0; j < 2; ++j){
    const int cki = (t>>3) + j*32, lo = (t&7)*8;
    u16x8 v;
    #pragma unroll
    for (int e = 0; e < 8; ++e) v[e] = tl[lo+e][cki];
    *(u16x8*)(Db + (long)(ck0+cki)*1024 + l0 + lo) = v;
  }
}

// ---------------------------------------------------------------------------
// XCD-aware bijective block swizzle (T1, m204).
// ---------------------------------------------------------------------------
__device__ __forceinline__ void xcd_map(int gxl, int gyl, int n8l,
                                        int& bx, int& by, int& bz){
  const int s = blockIdx.x + (blockIdx.y<<gxl) + (blockIdx.z<<(gxl+gyl));
  const int orig = ((s & 7) << n8l) + (s >> 3);
  bx = orig & ((1<<gxl)-1);
  by = (orig >> gxl) & ((1<<gyl)-1);
  bz = orig >> (gxl+gyl);
}

// ---------------------------------------------------------------------------
// 64x128-tile bf16 MFMA GEMM, counted-vmcnt triple-buffer K-loop (T3/T4-lite):
// loads for 2 tiles stay in flight across raw s_barriers; per-iter wait is
// vmcnt(3) (own current-tile loads), vmcnt(0) only on the last iteration.
// LDS chunk-XOR swizzle (T2) on source + read. setprio around MFMA (T5).
// EPI 0: fp32 C. EPI 2: bf16 C^T [N][M] + fused BN stats.
// ---------------------------------------------------------------------------
template<int EPI>
__global__ __launch_bounds__(256,4) void gemm_bt64(
    const u16* __restrict__ A, long sA,
    const u16* __restrict__ B, long sB, const int zshB,
    void* __restrict__ Cv, long sC,
    const int M, const int N, const int K,
    float* __restrict__ bnstats,
    const int gxl, const int gyl, const int n8l)
{
  int bx, by, bI;
  xcd_map(gxl, gyl, n8l, bx, by, bI);
  const u16* Ab = A + (long)bI*sA;
  const u16* Bb = B + (long)(bI>>zshB)*sB;
  const int m0 = bx*64, n0 = by*128;
  __shared__ __align__(16) u16 As[6144];    // 3 x [64][32]  (12KB)
  __shared__ __align__(16) u16 Bs[12288];   // 3 x [128][32] (24KB)
  const int t = threadIdx.x, lane = t & 63, wv = t >> 6;
  const int wm = (wv>>1)*32, wn = (wv&1)*64;
  const int fr = lane & 15, fo = lane >> 4;
  const int fosw = (fo ^ ((fr & 3) ^ ((fr >> 2) & 3))) * 8;   // swizzled read col
  f32x4 acc[2][4] = {};
  const int ca  = wv*64 + lane;
  const int cb0 = wv*128 + lane, cb1 = cb0 + 64;
  const u16* Ag  = Ab + (long)(m0 + (ca >>2))*K + gswz(ca);
  const u16* Bg0 = Bb + (long)(n0 + (cb0>>2))*K + gswz(cb0);
  const u16* Bg1 = Bb + (long)(n0 + (cb1>>2))*K + gswz(cb1);
#define STAGE64(slot, kofs) { \
    gload_lds16(Ag  + (kofs), &As[(slot)*2048 + wv*512]); \
    gload_lds16(Bg0 + (kofs), &Bs[(slot)*4096 + wv*1024]); \
    gload_lds16(Bg1 + (kofs), &Bs[(slot)*4096 + wv*1024 + 512]); }
  STAGE64(0, 0)
  STAGE64(1, 32)
  const int nk = K >> 5;
  int sl = 0;
  for (int ki = 0; ki < nk; ++ki){
    if (ki + 1 < nk) asm volatile("s_waitcnt vmcnt(3)\n\ts_barrier" ::: "memory");
    else             asm volatile("s_waitcnt vmcnt(0)\n\ts_barrier" ::: "memory");
    if (ki + 2 < nk){
      const int s2 = (sl >= 1) ? sl - 1 : sl + 2;
      STAGE64(s2, (ki + 2) << 5)
    }
    const int ra = sl*2048, rb = sl*4096;
    bf16x8 af[2], bfv[4];
    #pragma unroll
    for (int i = 0; i < 2; ++i)
      af[i]  = *(const bf16x8*)&As[ra + (wm + i*16 + fr)*32 + fosw];
    #pragma unroll
    for (int i = 0; i < 4; ++i)
      bfv[i] = *(const bf16x8*)&Bs[rb + (wn + i*16 + fr)*32 + fosw];
    __builtin_amdgcn_s_setprio(1);
    #pragma unroll
    for (int mi = 0; mi < 2; ++mi)
      #pragma unroll
      for (int ni = 0; ni < 4; ++ni)
        acc[mi][ni] = __builtin_amdgcn_mfma_f32_16x16x32_bf16(af[mi], bfv[ni], acc[mi][ni], 0, 0, 0);
    __builtin_amdgcn_s_setprio(0);
    sl = (sl + 1 == 3) ? 0 : sl + 1;
  }
#undef STAGE64
  if (EPI == 0){
    float* Cf = (float*)Cv + (long)bI*sC;
    #pragma unroll
    for (int mi = 0; mi < 2; ++mi)
      #pragma unroll
      for (int ni = 0; ni < 4; ++ni){
        const int col = n0 + wn + ni*16 + fr;
        #pragma unroll
        for (int r = 0; r < 4; ++r){
          const int row = m0 + wm + mi*16 + fo*4 + r;
          Cf[(long)row*N + col] = acc[mi][ni][r];
        }
      }
  } else {
    // bf16 C^T [N][M] + fused BN stats
    u16* Cb = (u16*)Cv + (long)bI*sC;
    #pragma unroll
    for (int mi = 0; mi < 2; ++mi)
      #pragma unroll
      for (int ni = 0; ni < 4; ++ni){
        const int col = n0 + wn + ni*16 + fr;
        const int row0 = m0 + wm + mi*16 + fo*4;
        u16x4 o;
        #pragma unroll
        for (int r = 0; r < 4; ++r) o[r] = f2bf(acc[mi][ni][r]);
        *(u16x4*)&Cb[(long)col*M + row0] = o;
      }
    const int sel = bI >> 2;
    float* sums = bnstats + sel*2048;
    #pragma unroll
    for (int ni = 0; ni < 4; ++ni){
      float s = 0.f, q = 0.f;
      #pragma unroll
      for (int mi = 0; mi < 2; ++mi)
        #pragma unroll
        for (int r = 0; r < 4; ++r){
          const float v = acc[mi][ni][r];
          s += v; q += v*v;
        }
      s += __shfl_xor(s, 16); s += __shfl_xor(s, 32);
      q += __shfl_xor(q, 16); q += __shfl_xor(q, 32);
      if (fo == 0){
        const int col = n0 + wn + ni*16 + fr;
        atomicAdd(&sums[col], s);
        atomicAdd(&sums[1024 + col], q);
      }
    }
  }
}

// ---------------------------------------------------------------------------
// 128x128-tile GEMM (attn@V): counted-vmcnt triple-buffer, T2 swizzle, T5.
// NHWC-fold bf16 epilogue.
// ---------------------------------------------------------------------------
__global__ __launch_bounds__(256,3) void gemm_bt(
    const u16* __restrict__ A, long sA,
    const u16* __restrict__ B, long sB,
    void* __restrict__ Cv,
    const int M, const int N, const int K,
    const int gxl, const int gyl, const int n8l)
{
  int bx, by, bI;
  xcd_map(gxl, gyl, n8l, bx, by, bI);
  const u16* Ab = A + (long)bI*sA;
  const u16* Bb = B + (long)bI*sB;
  const int m0 = bx*128, n0 = by*128;
  __shared__ __align__(16) u16 As[12288];   // 3 x [128][32] (24KB)
  __shared__ __align__(16) u16 Bs[12288];
  const int t = threadIdx.x, lane = t & 63, wv = t >> 6;
  const int wm = (wv>>1)*64, wn = (wv&1)*64;
  const int fr = lane & 15, fo = lane >> 4;
  const int fosw = (fo ^ ((fr & 3) ^ ((fr >> 2) & 3))) * 8;
  f32x4 acc[4][4] = {};
  const int c0 = wv*128 + lane, c1 = c0 + 64;
  const u16* Ag0 = Ab + (long)(m0 + (c0>>2))*K + gswz(c0);
  const u16* Ag1 = Ab + (long)(m0 + (c1>>2))*K + gswz(c1);
  const u16* Bg0 = Bb + (long)(n0 + (c0>>2))*K + gswz(c0);
  const u16* Bg1 = Bb + (long)(n0 + (c1>>2))*K + gswz(c1);
#define STAGE128(slot, kofs) { \
    u16* a_ = &As[(slot)*4096 + wv*1024]; \
    u16* b_ = &Bs[(slot)*4096 + wv*1024]; \
    gload_lds16(Ag0 + (kofs), a_); \
    gload_lds16(Ag1 + (kofs), a_ + 512); \
    gload_lds16(Bg0 + (kofs), b_); \
    gload_lds16(Bg1 + (kofs), b_ + 512); }
  STAGE128(0, 0)
  STAGE128(1, 32)
  const int nk = K >> 5;
  int sl = 0;
  for (int ki = 0; ki < nk; ++ki){
    if (ki + 1 < nk) asm volatile("s_waitcnt vmcnt(4)\n\ts_barrier" ::: "memory");
    else             asm volatile("s_waitcnt vmcnt(0)\n\ts_barrier" ::: "memory");
    if (ki + 2 < nk){
      const int s2 = (sl >= 1) ? sl - 1 : sl + 2;
      STAGE128(s2, (ki + 2) << 5)
    }
    const int ro = sl*4096;
    bf16x8 af[4], bfv[4];
    #pragma unroll
    for (int i = 0; i < 4; ++i){
      af[i]  = *(const bf16x8*)&As[ro + (wm + i*16 + fr)*32 + fosw];
      bfv[i] = *(const bf16x8*)&Bs[ro + (wn + i*16 + fr)*32 + fosw];
    }
    __builtin_amdgcn_s_setprio(1);
    #pragma unroll
    for (int mi = 0; mi < 4; ++mi)
      #pragma unroll
      for (int ni = 0; ni < 4; ++ni)
        acc[mi][ni] = __builtin_amdgcn_mfma_f32_16x16x32_bf16(af[mi], bfv[ni], acc[mi][ni], 0, 0, 0);
    __builtin_amdgcn_s_setprio(0);
    sl = (sl + 1 == 3) ? 0 : sl + 1;
  }
#undef STAGE128
  // fold to NHWC: row=l=hb*32+wb, col=ck=c*64+kh*8+kw -> O[b][(hb*8+kh)*256+wb*8+kw][c]
  u16* O = (u16*)Cv;
  #pragma unroll
  for (int mi = 0; mi < 4; ++mi)
    #pragma unroll
    for (int ni = 0; ni < 4; ++ni){
      const int col = n0 + wn + ni*16 + fr;
      const int c = col >> 6, khh = (col>>3)&7, kww = col&7;
      #pragma unroll
      for (int r = 0; r < 4; ++r){
        const int row = m0 + wm + mi*16 + fo*4 + r;
        const int hb = row >> 5, wbb = row & 31;
        O[(((long)bI*65536 + (hb*8+khh)*256 + wbb*8 + kww)<<6) + c] = f2bf(acc[mi][ni][r]);
      }
    }
}

// ---------------------------------------------------------------------------
// ff1: C[262144][256] = X[262144][64] * W1b^T, bias+GELU, bf16 out. No LDS.
// ---------------------------------------------------------------------------
__global__ __launch_bounds__(256,3) void ff1_mfma(
    const u16* __restrict__ X, const u16* __restrict__ W1b,
    const float* __restrict__ B1, u16* __restrict__ H1)
{
  const int t = threadIdx.x, lane = t & 63, wv = t >> 6;
  const long m0 = (long)blockIdx.x*128 + (wv>>1)*64;
  const int n0 = blockIdx.y*128 + (wv&1)*64;
  const int fr = lane & 15, fo = lane >> 4;
  f32x4 acc[4][4] = {};
  #pragma unroll
  for (int k0 = 0; k0 < 64; k0 += 32){
    bf16x8 af[4], bfv[4];
    #pragma unroll
    for (int i = 0; i < 4; ++i){
      af[i]  = *(const bf16x8*)(X   + (m0 + i*16 + fr)*64 + k0 + fo*8);
      bfv[i] = *(const bf16x8*)(W1b + (long)(n0 + i*16 + fr)*64 + k0 + fo*8);
    }
    #pragma unroll
    for (int mi = 0; mi < 4; ++mi)
      #pragma unroll
      for (int ni = 0; ni < 4; ++ni)
        acc[mi][ni] = __builtin_amdgcn_mfma_f32_16x16x32_bf16(af[mi], bfv[ni], acc[mi][ni], 0, 0, 0);
  }
  #pragma unroll
  for (int ni = 0; ni < 4; ++ni){
    const int col = n0 + ni*16 + fr;
    const float bc = B1[col];
    #pragma unroll
    for (int mi = 0; mi < 4; ++mi){
      const long row = m0 + mi*16 + fo*4;
      #pragma unroll
      for (int r = 0; r < 4; ++r)
        H1[(row + r)*256 + col] = f2bf(gelu_f(acc[mi][ni][r] + bc));
    }
  }
}

// ---------------------------------------------------------------------------
// ff2: C[262144][64] = H1[262144][256] * W2b^T, bias+GELU+residual, fp32 NCHW.
// ---------------------------------------------------------------------------
__global__ __launch_bounds__(256,3) void ff2_mfma(
    const u16* __restrict__ H1, const u16* __restrict__ W2b,
    const float* __restrict__ B2, const float* __restrict__ F,
    float* __restrict__ OUT)
{
  const int t = threadIdx.x, lane = t & 63, wv = t >> 6;
  const long m0 = (long)blockIdx.x*256 + wv*64;
  const int fr = lane & 15, fo = lane >> 4;
  f32x4 acc[4][4] = {};
  for (int k0 = 0; k0 < 256; k0 += 32){
    bf16x8 af[4], bfv[4];
    #pragma unroll
    for (int i = 0; i < 4; ++i){
      af[i]  = *(const bf16x8*)(H1  + (m0 + i*16 + fr)*256 + k0 + fo*8);
      bfv[i] = *(const bf16x8*)(W2b + (long)(i*16 + fr)*256 + k0 + fo*8);
    }
    #pragma unroll
    for (int mi = 0; mi < 4; ++mi)
      #pragma unroll
      for (int ni = 0; ni < 4; ++ni)
        acc[mi][ni] = __builtin_amdgcn_mfma_f32_16x16x32_bf16(af[mi], bfv[ni], acc[mi][ni], 0, 0, 0);
  }
  #pragma unroll
  for (int ni = 0; ni < 4; ++ni){
    const int c = ni*16 + fr;
    const float bc = B2[c];
    #pragma unroll
    for (int mi = 0; mi < 4; ++mi){
      const long p = m0 + mi*16 + fo*4;
      const int b = (int)(p >> 16), pp = (int)(p & 65535);
      const long idx = ((long)(b*64 + c))*65536 + pp;
      const f4 fres = *(const f4*)&F[idx];
      f4 o;
      #pragma unroll
      for (int r = 0; r < 4; ++r) o[r] = gelu_f(acc[mi][ni][r] + bc) + fres[r];
      *(f4*)&OUT[idx] = o;
    }
  }
}

// ---------------------------------------------------------------------------
__global__ __launch_bounds__(256) void cvt_w(
    const float* __restrict__ Wq, const float* __restrict__ Wk,
    u16* __restrict__ Oq, u16* __restrict__ Ok)
{
  const long i = ((long)blockIdx.x*256 + threadIdx.x)*4;
  const float* s = blockIdx.y ? Wk : Wq;
  u16* d = blockIdx.y ? Ok : Oq;
  f4 v = *(const f4*)&s[i];
  u16x4 o; o[0]=f2bf(v[0]); o[1]=f2bf(v[1]); o[2]=f2bf(v[2]); o[3]=f2bf(v[3]);
  *(u16x4*)&d[i] = o;
}

__global__ __launch_bounds__(256) void cvt_ffw(
    const float* __restrict__ W1, const float* __restrict__ W2,
    u16* __restrict__ O1, u16* __restrict__ O2)
{
  const long i = ((long)blockIdx.x*256 + threadIdx.x)*4;
  const float* s = blockIdx.y ? W2 : W1;
  u16* d = blockIdx.y ? O2 : O1;
  f4 v = *(const f4*)&s[i];
  u16x4 o; o[0]=f2bf(v[0]); o[1]=f2bf(v[1]); o[2]=f2bf(v[2]); o[3]=f2bf(v[3]);
  *(u16x4*)&d[i] = o;
}

// ---------------------------------------------------------------------------
// BN finalize (stats from fused GEMM epilogue).
// ---------------------------------------------------------------------------
__global__ void bn_fin2(float* __restrict__ stats,
                        const float* __restrict__ gq, const float* __restrict__ bq,
                        const float* __restrict__ gk, const float* __restrict__ bk)
{
  const int sel = blockIdx.y;
  const int d = blockIdx.x*256 + threadIdx.x;
  if (d >= 1024) return;
  const float* sum   = stats + sel*2048;
  const float* sumsq = sum + 1024;
  const float* g    = sel ? gk : gq;
  const float* beta = sel ? bk : bq;
  const float m  = sum[d]   * (1.f/4096.f);
  const float vv = sumsq[d] * (1.f/4096.f) - m*m;
  const float sc = g[d] * rsqrtf(vv + 1e-5f);
  stats[4096 + sel*2048 + d]        = sc;
  stats[4096 + sel*2048 + 1024 + d] = beta[d] - m*sc;
}

// ---------------------------------------------------------------------------
// BN apply + transpose: QT [z][d=1024][l=1024] bf16 -> Y [z][l][d] bf16.
// ---------------------------------------------------------------------------
__global__ __launch_bounds__(256) void bn_apply_t(
    const u16* __restrict__ QT, const float* __restrict__ stats,
    u16* __restrict__ Y)
{
  __shared__ u16 tl[64][72];
  const int t = threadIdx.x, zi = blockIdx.z;
  const int d0 = blockIdx.x*64, l0 = blockIdx.y*64;
  const int sel = zi >> 2;
  const u16* S = QT + (long)zi*1048576;
  u16* D = Y + (long)zi*1048576;
  const float* scp = stats + 4096 + sel*2048;
  const float* shp = scp + 1024;
  #pragma unroll
  for (int j = 0; j < 2; ++j){
    const int di = (t>>3) + j*32, lo = (t&7)*8;
    const int d = d0 + di;
    const float sc = scp[d], sh = shp[d];
    u16x8 v = *(const u16x8*)(S + (long)d*1024 + l0 + lo);
    u16x8 o;
    #pragma unroll
    for (int e = 0; e < 8; ++e) o[e] = f2bf(bf2f(v[e])*sc + sh);
    *(u16x8*)&tl[di][lo] = o;
  }
  __syncthreads();
  #pragma unroll
  for (int j = 0; j < 2; ++j){
    const int li = (t>>3) + j*32, dof = (t&7)*8;
    u16x8 v;
    #pragma unroll
    for (int e = 0; e < 8; ++e) v[e] = tl[dof+e][li];
    *(u16x8*)(D + (long)(l0+li)*1024 + d0 + dof) = v;
  }
}

__global__ __launch_bounds__(256) void softmax_k(
    const float* __restrict__ S, u16* __restrict__ P)
{
  const long row = blockIdx.x;
  const float* p = S + row*1024;
  const int t = threadIdx.x;
  f4 v = *(const f4*)&p[t*4];
  v *= 0.03125f;
  float mx = fmaxf(fmaxf(v[0],v[1]), fmaxf(v[2],v[3]));
  #pragma unroll
  for (int o = 1; o < 64; o <<= 1) mx = fmaxf(mx, __shfl_xor(mx, o));
  __shared__ float red[4], red2[4];
  if ((t & 63) == 0) red[t>>6] = mx;
  __syncthreads();
  mx = fmaxf(fmaxf(red[0],red[1]), fmaxf(red[2],red[3]));
  f4 e;
  e[0]=__expf(v[0]-mx); e[1]=__expf(v[1]-mx); e[2]=__expf(v[2]-mx); e[3]=__expf(v[3]-mx);
  float sm = e[0]+e[1]+e[2]+e[3];
  #pragma unroll
  for (int o = 1; o < 64; o <<= 1) sm += __shfl_xor(sm, o);
  if ((t & 63) == 0) red2[t>>6] = sm;
  __syncthreads();
  sm = red2[0]+red2[1]+red2[2]+red2[3];
  const float inv = 1.0f/sm;
  u16x4 o4; o4[0]=f2bf(e[0]*inv); o4[1]=f2bf(e[1]*inv); o4[2]=f2bf(e[2]*inv); o4[3]=f2bf(e[3]*inv);
  *(u16x4*)&P[row*1024 + t*4] = o4;
}

// ---------------------------------------------------------------------------
extern "C" void kernel_launch(void* const* d_in, const int* in_sizes, int n_in,
                              void* d_out, int out_size, void* d_ws, size_t ws_size,
                              hipStream_t stream)
{
  const float* feat  = (const float*)d_in[0];
  const float* w_enc = (const float*)d_in[1];
  const float* b_enc = (const float*)d_in[2];
  const float* w_k   = (const float*)d_in[3];
  const float* b_k   = (const float*)d_in[4];
  const float* w_v   = (const float*)d_in[5];
  const float* b_v   = (const float*)d_in[6];
  const float* fcq_w = (const float*)d_in[7];
  // d_in[8] fcq_b, d_in[10] fck_b: cancelled exactly by train-mode BN.
  const float* fck_w = (const float*)d_in[9];
  const float* bnq_g = (const float*)d_in[11];
  const float* bnq_b = (const float*)d_in[12];
  const float* bnk_g = (const float*)d_in[13];
  const float* bnk_b = (const float*)d_in[14];
  const float* ff1w  = (const float*)d_in[15];
  const float* ff1b  = (const float*)d_in[16];
  const float* ff2w  = (const float*)d_in[17];
  const float* ff2b  = (const float*)d_in[18];

  char* ws = (char*)d_ws;
  u16*   Aq      = (u16*)  (ws);                   // [0,32)  MB [B][L][4096] (Ak follows)
  u16*   Ak      = (u16*)  (ws + (32ull<<20));     // [32,64)
  u16*   Vc      = (u16*)  (ws + (64ull<<20));     // [64,96)  [B][4096][L]
  u16*   Wq      = (u16*)  (ws + (96ull<<20));     // [96,104)  (Wk follows)
  u16*   Wk      = (u16*)  (ws + (104ull<<20));    // [104,112)
  u16*   q_bf    = (u16*)  (ws + (112ull<<20));    // [112,120) (k_bf follows)
  u16*   k_bf    = (u16*)  (ws + (120ull<<20));    // [120,128)
  u16*   qk_rawT = (u16*)  (ws + (128ull<<20));    // [128,144) bf16 pre-BN q|k C^T [z][d][l]
  float* scores  = (float*)(ws + (160ull<<20));    // [160,176)
  u16*   attn    = (u16*)  (ws + (176ull<<20));    // [176,184)
  u16*   out_nhwc= (u16*)  (ws + (184ull<<20));    // [184,216) [B][65536][64]
  u16*   NX      = (u16*)  (ws + (128ull<<20));    // [128,160) transient (dead before qk_rawT)
  u16*   Vl      = (u16*)  (ws + (160ull<<20));    // [160,192) transient (dead before scores)
  u16*   Wt2     = (u16*)  (ws + (216ull<<20));    // +221KB
  float* stats   = (float*)(ws + (217ull<<20));    // 32KB
  u16*   W1b     = (u16*)  (ws + (218ull<<20));    // 32KB [256][64] bf16
  u16*   W2b     = (u16*)  (ws + (218ull<<20) + 65536); // 32KB [64][256] bf16
  u16*   h1      = (u16*)  (ws);                   // [0,128) reuse (Aq..k_bf dead by ff1)

  hipMemsetAsync(stats, 0, 4096*sizeof(float), stream);

  to_nhwc<<<dim3(1024,4), 256, 0, stream>>>(feat, NX);
  wt_prep<<<dim3(432), 256, 0, stream>>>(w_enc, w_k, w_v, Wt2);
  conv_mfma<<<dim3(16,32,4), 512, 0, stream>>>(NX, Wt2, b_enc, b_k, b_v, Aq, Ak, Vl);
  v_tr<<<dim3(64,16,4), 256, 0, stream>>>(Vl, Vc);
  cvt_w<<<dim3(4096,2), 256, 0, stream>>>(fcq_w, fck_w, Wq, Wk);
  cvt_ffw<<<dim3(16,2), 256, 0, stream>>>(ff1w, ff2w, W1b, W2b);

  // merged q+k projections (z 0..3: q, 4..7: k), bf16 C^T + fused BN stats
  gemm_bt64<2><<<dim3(16,8,8), 256, 0, stream>>>(Aq, 4194304, Wq, 4194304, 2,
                                                 qk_rawT, 1048576, 1024, 1024, 4096, stats,
                                                 4, 3, 7);

  bn_fin2<<<dim3(4,2), 256, 0, stream>>>(stats, bnq_g, bnq_b, bnk_g, bnk_b);
  bn_apply_t<<<dim3(16,16,8), 256, 0, stream>>>(qk_rawT, stats, q_bf);

  gemm_bt64<0><<<dim3(16,8,4), 256, 0, stream>>>(q_bf, 1048576, k_bf, 1048576, 0,
                                                 scores, 1048576, 1024, 1024, 1024, nullptr,
                                                 4, 3, 6);
  softmax_k<<<dim3(4096), 256, 0, stream>>>(scores, attn);

  gemm_bt<<<dim3(8,32,4), 256, 0, stream>>>(attn, 1048576, Vc, 4194304,
                                            out_nhwc, 1024, 4096, 1024,
                                            3, 5, 7);

  ff1_mfma<<<dim3(2048,2), 256, 0, stream>>>(out_nhwc, W1b, ff1b, h1);
  ff2_mfma<<<dim3(1024), 256, 0, stream>>>(h1, W2b, ff2b, feat, (float*)d_out);
}

// Round 14
// 523.204 us; speedup vs baseline: 1.0418x; 1.0418x over previous
//
#include <hip/hip_runtime.h>

typedef unsigned short u16;
typedef float f4 __attribute__((ext_vector_type(4)));
typedef float f32x4 __attribute__((ext_vector_type(4)));
typedef short bf16x8 __attribute__((ext_vector_type(8)));
typedef u16 u16x8 __attribute__((ext_vector_type(8)));
typedef u16 u16x4 __attribute__((ext_vector_type(4)));

__device__ __forceinline__ u16 f2bf(float f){
  unsigned u = __float_as_uint(f);
  u = (u + 0x7FFFu + ((u>>16)&1u)) >> 16;
  return (u16)u;
}
__device__ __forceinline__ float bf2f(u16 u){
  return __uint_as_float(((unsigned)u)<<16);
}
// tanh-form GELU: max |dev| vs exact erf-GELU ~1e-3 (threshold is 0.108).
__device__ __forceinline__ float gelu_f(float x){
  float y = 1.5957691216057308f*(x + 0.044715f*x*x*x);
  y = fminf(y, 30.0f);
  float t = __expf(y);
  float r = __builtin_amdgcn_rcpf(t + 1.0f);
  return 0.5f*x*(1.0f + (t - 1.0f)*r);
}

// async global->LDS 16B (LDS dest is wave-uniform base + lane*16)
typedef __attribute__((address_space(1))) const unsigned int as1_cuint;
typedef __attribute__((address_space(3))) unsigned int as3_uint;
__device__ __forceinline__ void gload_lds16(const void* g, void* l){
  __builtin_amdgcn_global_load_lds((as1_cuint*)g, (as3_uint*)l, 16, 0, 0);
}

// ---------------------------------------------------------------------------
// feat NCHW fp32 -> NHWC bf16  ([4][256][256][64])
// ---------------------------------------------------------------------------
__global__ __launch_bounds__(256) void to_nhwc(
    const float* __restrict__ F, u16* __restrict__ O)
{
  __shared__ float tile[64][65];
  const int t = threadIdx.x, b = blockIdx.y;
  const long px0 = (long)blockIdx.x*64;
  const float* Fb = F + (long)b*64*65536;
  #pragma unroll
  for (int i = 0; i < 4; ++i){
    const int ch = (t>>4) + i*16;
    const int pxo = (t&15)*4;
    f4 v = *(const f4*)&Fb[(long)ch*65536 + px0 + pxo];
    tile[ch][pxo]=v[0]; tile[ch][pxo+1]=v[1]; tile[ch][pxo+2]=v[2]; tile[ch][pxo+3]=v[3];
  }
  __syncthreads();
  const int px = t & 63, ch0 = (t>>6)*16;
  u16x8 o0, o1;
  #pragma unroll
  for (int j = 0; j < 8; ++j){ o0[j]=f2bf(tile[ch0+j][px]); o1[j]=f2bf(tile[ch0+8+j][px]); }
  u16* Ob = O + ((long)b*65536 + px0 + px)*64 + ch0;
  *(u16x8*)Ob = o0; *(u16x8*)(Ob+8) = o1;
}

// ---------------------------------------------------------------------------
// conv weights -> Wt2[((dy*3+dx)*2+kc)*192 + n][32]  (fragment-contiguous bf16)
// ---------------------------------------------------------------------------
__global__ __launch_bounds__(256) void wt_prep(
    const float* __restrict__ we, const float* __restrict__ wk,
    const float* __restrict__ wv, u16* __restrict__ Wt2)
{
  const int i = blockIdx.x*256 + threadIdx.x;   // 110592 total
  const int cio = i & 31;
  const int t1 = i >> 5;
  const int n  = t1 % 192;
  const int t2 = t1 / 192;
  const int kc = t2 & 1, p = t2 >> 1;
  const int dy = p/3, dx = p - dy*3;
  const int ci = kc*32 + cio;
  const float* W = (n < 64) ? we : (n < 128) ? wk : wv;
  const int co = n & 63;
  Wt2[i] = f2bf(W[((co*64 + ci)*3 + dy)*3 + dx]);
}

// ---------------------------------------------------------------------------
// MFMA implicit-GEMM conv (512 thr, 2 blocks/CU, two-phase LDS epilogue).
// ---------------------------------------------------------------------------
__global__ __launch_bounds__(512,2) void conv_mfma(
    const u16* __restrict__ X, const u16* __restrict__ Wt2,
    const float* __restrict__ be, const float* __restrict__ bk, const float* __restrict__ bv,
    u16* __restrict__ Aq, u16* __restrict__ Ak, u16* __restrict__ Vl)
{
  __shared__ __align__(16) u16 smem[24576];   // 48KB: halo / epilogue reuse
  const int t = threadIdx.x, lane = t & 63, wvi = t >> 6;
  const int bx = blockIdx.x, by = blockIdx.y, b = blockIdx.z;
  const int x0 = bx*16, y0 = by*8;
  const u16* Xb = X + (long)b*4194304;

  #pragma unroll
  for (int j = 0; j < 3; ++j){
    const int id = t + j*512;
    if (id < 1440){
      const int row = id / 144, rem = id - row*144, col = rem >> 3, ck = rem & 7;
      const int y = y0 - 1 + row, x = x0 - 1 + col;
      int4 v = {0,0,0,0};
      if ((unsigned)y < 256u && (unsigned)x < 256u)
        v = *(const int4*)(Xb + ((long)y*256 + x)*64 + ck*8);
      *(int4*)&smem[((row*18 + col)*8 + (ck ^ (col&7)))*8] = v;
    }
  }
  __syncthreads();

  const int wm4 = (wvi>>2)*4;
  const int wn  = (wvi&3)*48;
  const int fr = lane & 15, fo = lane >> 4;
  f32x4 acc[4][3] = {};

  #pragma unroll
  for (int dy = 0; dy < 3; ++dy)
  #pragma unroll
  for (int dx = 0; dx < 3; ++dx){
    const int p = dy*3 + dx;
    #pragma unroll
    for (int kc = 0; kc < 2; ++kc){
      bf16x8 af[4], bfv[3];
      const u16* wp = Wt2 + ((long)(p*2 + kc)*192 + wn + fr)*32 + fo*8;
      #pragma unroll
      for (int ni = 0; ni < 3; ++ni)
        bfv[ni] = *(const bf16x8*)(wp + ni*16*32);
      #pragma unroll
      for (int mi = 0; mi < 4; ++mi){
        const int row = wm4 + mi + dy;
        const int col = fr + dx;
        af[mi] = *(const bf16x8*)&smem[((row*18 + col)*8 + ((kc*4+fo) ^ (col&7)))*8];
      }
      #pragma unroll
      for (int mi = 0; mi < 4; ++mi)
        #pragma unroll
        for (int ni = 0; ni < 3; ++ni)
          acc[mi][ni] = __builtin_amdgcn_mfma_f32_16x16x32_bf16(af[mi], bfv[ni], acc[mi][ni], 0, 0, 0);
    }
  }
  __syncthreads();

  // phase 1: bias+GELU, frags -> LDS
  const int c0 = fo*4;
  const int lloc = c0 >> 3, kw0 = c0 & 7;
  #pragma unroll
  for (int ni = 0; ni < 3; ++ni){
    const int n = wn + ni*16 + fr;
    const int mat = n >> 6, co = n & 63;
    const float bias = (mat==0) ? be[co] : (mat==1) ? bk[co] : bv[co];
    #pragma unroll
    for (int mi = 0; mi < 4; ++mi){
      const int r = wm4 + mi;
      u16x4 o;
      #pragma unroll
      for (int rg = 0; rg < 4; ++rg) o[rg] = f2bf(gelu_f(acc[mi][ni][rg] + bias));
      const int e = ((mat*2 + lloc)*64 + co)*64 + ((r*8 + kw0) ^ ((co&7)<<3));
      *(u16x4*)&smem[e] = o;
    }
  }
  __syncthreads();

  // phase 2: six contiguous 8KB rows, 16B/lane coalesced
  const int l_lo = by*32 + bx*2;
  const int co_r = t >> 3, sw = (t&7) ^ (co_r&7);
  const int eoff = co_r*64 + sw*8;
  #pragma unroll
  for (int i = 0; i < 6; ++i){
    const int mat = i >> 1, ll = i & 1;
    u16x8 v = *(const u16x8*)&smem[(mat*2 + ll)*4096 + eoff];
    u16* dst = (mat==0 ? Aq : mat==1 ? Ak : Vl)
             + ((long)b*1024 + l_lo + ll)*4096 + t*8;
    *(u16x8*)dst = v;
  }
}

// ---------------------------------------------------------------------------
// V transpose: [b][l=1024][ck=4096] -> [b][ck][l]
// ---------------------------------------------------------------------------
__global__ __launch_bounds__(256) void v_tr(
    const u16* __restrict__ S, u16* __restrict__ D)
{
  __shared__ u16 tl[64][72];
  const int t = threadIdx.x, b = blockIdx.z;
  const int ck0 = blockIdx.x*64, l0 = blockIdx.y*64;
  const u16* Sb = S + (long)b*4194304;
  u16* Db = D + (long)b*4194304;
  #pragma unroll
  for (int j = 0; j < 2; ++j){
    const int li = (t>>3) + j*32, cko = (t&7)*8;
    *(u16x8*)&tl[li][cko] = *(const u16x8*)(Sb + (long)(l0+li)*4096 + ck0 + cko);
  }
  __syncthreads();
  #pragma unroll
  for (int j = 0; j < 2; ++j){
    const int cki = (t>>3) + j*32, lo = (t&7)*8;
    u16x8 v;
    #pragma unroll
    for (int e = 0; e < 8; ++e) v[e] = tl[lo+e][cki];
    *(u16x8*)(Db + (long)(ck0+cki)*1024 + l0 + lo) = v;
  }
}

// ---------------------------------------------------------------------------
// XCD-aware bijective block swizzle (T1, m204).
// ---------------------------------------------------------------------------
__device__ __forceinline__ void xcd_map(int gxl, int gyl, int n8l,
                                        int& bx, int& by, int& bz){
  const int s = blockIdx.x + (blockIdx.y<<gxl) + (blockIdx.z<<(gxl+gyl));
  const int orig = ((s & 7) << n8l) + (s >> 3);
  bx = orig & ((1<<gxl)-1);
  by = (orig >> gxl) & ((1<<gyl)-1);
  bz = orig >> (gxl+gyl);
}

// ---------------------------------------------------------------------------
// Unified 128x128 bf16 MFMA GEMM, BK=64 per barrier: double-buffered
// 2-slot x 2-half LDS (64KB; each half keeps the proven linear [128][32]
// layout + fragment addressing). One __syncthreads per iteration; next-slot
// stage issued right after the barrier so its latency hides under 32 MFMA +
// 16 ds_reads (2x compute per barrier vs BK=32; barrier count halved).
// Slot written in iter i was last READ in iter i-1 before barrier i -> safe.
// EPI 0: fp32 C. EPI 1: NHWC fold bf16. EPI 2: bf16 C^T [N][M] + BN stats.
// ---------------------------------------------------------------------------
template<int EPI>
__global__ __launch_bounds__(256,2) void gemm_bt128(
    const u16* __restrict__ A, long sA,
    const u16* __restrict__ B, long sB, const int zshB,
    void* __restrict__ Cv, long sC,
    const int M, const int N, const int K,
    float* __restrict__ bnstats,
    const int gxl, const int gyl, const int n8l)
{
  int bx, by, bI;
  xcd_map(gxl, gyl, n8l, bx, by, bI);
  const u16* Ab = A + (long)bI*sA;
  const u16* Bb = B + (long)(bI>>zshB)*sB;
  const int m0 = bx*128, n0 = by*128;
  __shared__ __align__(16) u16 As[16384];   // [2 slot][2 half][128][32] = 32KB
  __shared__ __align__(16) u16 Bs[16384];
  const int t = threadIdx.x, lane = t & 63, wv = t >> 6;
  const int wm = (wv>>1)*64, wn = (wv&1)*64;
  const int fr = lane & 15, fo = lane >> 4;
  f32x4 acc[4][4] = {};
  const int c0 = wv*128 + lane, c1 = c0 + 64;
  const u16* Ag0 = Ab + (long)(m0 + (c0>>2))*K + (c0&3)*8;
  const u16* Ag1 = Ab + (long)(m0 + (c1>>2))*K + (c1&3)*8;
  const u16* Bg0 = Bb + (long)(n0 + (c0>>2))*K + (c0&3)*8;
  const u16* Bg1 = Bb + (long)(n0 + (c1>>2))*K + (c1&3)*8;
#define STAGEH(slot, h, kofs) { \
    u16* a_ = &As[(((slot)*2+(h))<<12) + wv*1024]; \
    u16* b_ = &Bs[(((slot)*2+(h))<<12) + wv*1024]; \
    const int ko_ = (kofs) + 32*(h); \
    gload_lds16(Ag0 + ko_, a_); \
    gload_lds16(Ag1 + ko_, a_ + 512); \
    gload_lds16(Bg0 + ko_, b_); \
    gload_lds16(Bg1 + ko_, b_ + 512); }
  STAGEH(0, 0, 0)
  STAGEH(0, 1, 0)
  const int nk = K >> 6;
  int cur = 0;
  for (int ki = 0; ki < nk; ++ki){
    __syncthreads();                      // slot-cur loads drained
    if (ki + 1 < nk){                     // prefetch next slot (covered by compute)
      const int k0 = (ki + 1) << 6;
      STAGEH(cur^1, 0, k0)
      STAGEH(cur^1, 1, k0)
    }
    #pragma unroll
    for (int h = 0; h < 2; ++h){
      const int ro = ((cur*2 + h) << 12);
      bf16x8 af[4], bfv[4];
      #pragma unroll
      for (int i = 0; i < 4; ++i){
        af[i]  = *(const bf16x8*)&As[ro + (wm + i*16 + fr)*32 + fo*8];
        bfv[i] = *(const bf16x8*)&Bs[ro + (wn + i*16 + fr)*32 + fo*8];
      }
      __builtin_amdgcn_s_setprio(1);
      #pragma unroll
      for (int mi = 0; mi < 4; ++mi)
        #pragma unroll
        for (int ni = 0; ni < 4; ++ni)
          acc[mi][ni] = __builtin_amdgcn_mfma_f32_16x16x32_bf16(af[mi], bfv[ni], acc[mi][ni], 0, 0, 0);
      __builtin_amdgcn_s_setprio(0);
    }
    cur ^= 1;
  }
#undef STAGEH
  if (EPI == 0){
    float* Cf = (float*)Cv + (long)bI*sC;
    #pragma unroll
    for (int mi = 0; mi < 4; ++mi)
      #pragma unroll
      for (int ni = 0; ni < 4; ++ni){
        const int col = n0 + wn + ni*16 + fr;
        #pragma unroll
        for (int r = 0; r < 4; ++r){
          const int row = m0 + wm + mi*16 + fo*4 + r;
          Cf[(long)row*N + col] = acc[mi][ni][r];
        }
      }
  } else if (EPI == 1) {
    // fold to NHWC: row=l=hb*32+wb, col=ck=c*64+kh*8+kw -> O[b][(hb*8+kh)*256+wb*8+kw][c]
    u16* O = (u16*)Cv;
    #pragma unroll
    for (int mi = 0; mi < 4; ++mi)
      #pragma unroll
      for (int ni = 0; ni < 4; ++ni){
        const int col = n0 + wn + ni*16 + fr;
        const int c = col >> 6, khh = (col>>3)&7, kww = col&7;
        #pragma unroll
        for (int r = 0; r < 4; ++r){
          const int row = m0 + wm + mi*16 + fo*4 + r;
          const int hb = row >> 5, wbb = row & 31;
          O[(((long)bI*65536 + (hb*8+khh)*256 + wbb*8 + kww)<<6) + c] = f2bf(acc[mi][ni][r]);
        }
      }
  } else {
    // bf16 C^T [N][M] + fused BN stats
    u16* Cb = (u16*)Cv + (long)bI*sC;
    #pragma unroll
    for (int mi = 0; mi < 4; ++mi)
      #pragma unroll
      for (int ni = 0; ni < 4; ++ni){
        const int col = n0 + wn + ni*16 + fr;
        const int row0 = m0 + wm + mi*16 + fo*4;
        u16x4 o;
        #pragma unroll
        for (int r = 0; r < 4; ++r) o[r] = f2bf(acc[mi][ni][r]);
        *(u16x4*)&Cb[(long)col*M + row0] = o;
      }
    const int sel = bI >> 2;
    float* sums = bnstats + sel*2048;
    #pragma unroll
    for (int ni = 0; ni < 4; ++ni){
      float s = 0.f, q = 0.f;
      #pragma unroll
      for (int mi = 0; mi < 4; ++mi)
        #pragma unroll
        for (int r = 0; r < 4; ++r){
          const float v = acc[mi][ni][r];
          s += v; q += v*v;
        }
      s += __shfl_xor(s, 16); s += __shfl_xor(s, 32);
      q += __shfl_xor(q, 16); q += __shfl_xor(q, 32);
      if (fo == 0){
        const int col = n0 + wn + ni*16 + fr;
        atomicAdd(&sums[col], s);
        atomicAdd(&sums[1024 + col], q);
      }
    }
  }
}

// ---------------------------------------------------------------------------
// ff1: C[262144][256] = X[262144][64] * W1b^T, bias+GELU, bf16 out. No LDS.
// ---------------------------------------------------------------------------
__global__ __launch_bounds__(256,3) void ff1_mfma(
    const u16* __restrict__ X, const u16* __restrict__ W1b,
    const float* __restrict__ B1, u16* __restrict__ H1)
{
  const int t = threadIdx.x, lane = t & 63, wv = t >> 6;
  const long m0 = (long)blockIdx.x*128 + (wv>>1)*64;
  const int n0 = blockIdx.y*128 + (wv&1)*64;
  const int fr = lane & 15, fo = lane >> 4;
  f32x4 acc[4][4] = {};
  #pragma unroll
  for (int k0 = 0; k0 < 64; k0 += 32){
    bf16x8 af[4], bfv[4];
    #pragma unroll
    for (int i = 0; i < 4; ++i){
      af[i]  = *(const bf16x8*)(X   + (m0 + i*16 + fr)*64 + k0 + fo*8);
      bfv[i] = *(const bf16x8*)(W1b + (long)(n0 + i*16 + fr)*64 + k0 + fo*8);
    }
    #pragma unroll
    for (int mi = 0; mi < 4; ++mi)
      #pragma unroll
      for (int ni = 0; ni < 4; ++ni)
        acc[mi][ni] = __builtin_amdgcn_mfma_f32_16x16x32_bf16(af[mi], bfv[ni], acc[mi][ni], 0, 0, 0);
  }
  #pragma unroll
  for (int ni = 0; ni < 4; ++ni){
    const int col = n0 + ni*16 + fr;
    const float bc = B1[col];
    #pragma unroll
    for (int mi = 0; mi < 4; ++mi){
      const long row = m0 + mi*16 + fo*4;
      #pragma unroll
      for (int r = 0; r < 4; ++r)
        H1[(row + r)*256 + col] = f2bf(gelu_f(acc[mi][ni][r] + bc));
    }
  }
}

// ---------------------------------------------------------------------------
// ff2: C[262144][64] = H1[262144][256] * W2b^T, bias+GELU+residual, fp32 NCHW.
// ---------------------------------------------------------------------------
__global__ __launch_bounds__(256,3) void ff2_mfma(
    const u16* __restrict__ H1, const u16* __restrict__ W2b,
    const float* __restrict__ B2, const float* __restrict__ F,
    float* __restrict__ OUT)
{
  const int t = threadIdx.x, lane = t & 63, wv = t >> 6;
  const long m0 = (long)blockIdx.x*256 + wv*64;
  const int fr = lane & 15, fo = lane >> 4;
  f32x4 acc[4][4] = {};
  for (int k0 = 0; k0 < 256; k0 += 32){
    bf16x8 af[4], bfv[4];
    #pragma unroll
    for (int i = 0; i < 4; ++i){
      af[i]  = *(const bf16x8*)(H1  + (m0 + i*16 + fr)*256 + k0 + fo*8);
      bfv[i] = *(const bf16x8*)(W2b + (long)(i*16 + fr)*256 + k0 + fo*8);
    }
    #pragma unroll
    for (int mi = 0; mi < 4; ++mi)
      #pragma unroll
      for (int ni = 0; ni < 4; ++ni)
        acc[mi][ni] = __builtin_amdgcn_mfma_f32_16x16x32_bf16(af[mi], bfv[ni], acc[mi][ni], 0, 0, 0);
  }
  #pragma unroll
  for (int ni = 0; ni < 4; ++ni){
    const int c = ni*16 + fr;
    const float bc = B2[c];
    #pragma unroll
    for (int mi = 0; mi < 4; ++mi){
      const long p = m0 + mi*16 + fo*4;
      const int b = (int)(p >> 16), pp = (int)(p & 65535);
      const long idx = ((long)(b*64 + c))*65536 + pp;
      const f4 fres = *(const f4*)&F[idx];
      f4 o;
      #pragma unroll
      for (int r = 0; r < 4; ++r) o[r] = gelu_f(acc[mi][ni][r] + bc) + fres[r];
      *(f4*)&OUT[idx] = o;
    }
  }
}

// ---------------------------------------------------------------------------
__global__ __launch_bounds__(256) void cvt_w(
    const float* __restrict__ Wq, const float* __restrict__ Wk,
    u16* __restrict__ Oq, u16* __restrict__ Ok)
{
  const long i = ((long)blockIdx.x*256 + threadIdx.x)*4;
  const float* s = blockIdx.y ? Wk : Wq;
  u16* d = blockIdx.y ? Ok : Oq;
  f4 v = *(const f4*)&s[i];
  u16x4 o; o[0]=f2bf(v[0]); o[1]=f2bf(v[1]); o[2]=f2bf(v[2]); o[3]=f2bf(v[3]);
  *(u16x4*)&d[i] = o;
}

__global__ __launch_bounds__(256) void cvt_ffw(
    const float* __restrict__ W1, const float* __restrict__ W2,
    u16* __restrict__ O1, u16* __restrict__ O2)
{
  const long i = ((long)blockIdx.x*256 + threadIdx.x)*4;
  const float* s = blockIdx.y ? W2 : W1;
  u16* d = blockIdx.y ? O2 : O1;
  f4 v = *(const f4*)&s[i];
  u16x4 o; o[0]=f2bf(v[0]); o[1]=f2bf(v[1]); o[2]=f2bf(v[2]); o[3]=f2bf(v[3]);
  *(u16x4*)&d[i] = o;
}

// ---------------------------------------------------------------------------
// BN finalize (stats from fused GEMM epilogue).
// ---------------------------------------------------------------------------
__global__ void bn_fin2(float* __restrict__ stats,
                        const float* __restrict__ gq, const float* __restrict__ bq,
                        const float* __restrict__ gk, const float* __restrict__ bk)
{
  const int sel = blockIdx.y;
  const int d = blockIdx.x*256 + threadIdx.x;
  if (d >= 1024) return;
  const float* sum   = stats + sel*2048;
  const float* sumsq = sum + 1024;
  const float* g    = sel ? gk : gq;
  const float* beta = sel ? bk : bq;
  const float m  = sum[d]   * (1.f/4096.f);
  const float vv = sumsq[d] * (1.f/4096.f) - m*m;
  const float sc = g[d] * rsqrtf(vv + 1e-5f);
  stats[4096 + sel*2048 + d]        = sc;
  stats[4096 + sel*2048 + 1024 + d] = beta[d] - m*sc;
}

// ---------------------------------------------------------------------------
// BN apply + transpose: QT [z][d=1024][l=1024] bf16 -> Y [z][l][d] bf16.
// ---------------------------------------------------------------------------
__global__ __launch_bounds__(256) void bn_apply_t(
    const u16* __restrict__ QT, const float* __restrict__ stats,
    u16* __restrict__ Y)
{
  __shared__ u16 tl[64][72];
  const int t = threadIdx.x, zi = blockIdx.z;
  const int d0 = blockIdx.x*64, l0 = blockIdx.y*64;
  const int sel = zi >> 2;
  const u16* S = QT + (long)zi*1048576;
  u16* D = Y + (long)zi*1048576;
  const float* scp = stats + 4096 + sel*2048;
  const float* shp = scp + 1024;
  #pragma unroll
  for (int j = 0; j < 2; ++j){
    const int di = (t>>3) + j*32, lo = (t&7)*8;
    const int d = d0 + di;
    const float sc = scp[d], sh = shp[d];
    u16x8 v = *(const u16x8*)(S + (long)d*1024 + l0 + lo);
    u16x8 o;
    #pragma unroll
    for (int e = 0; e < 8; ++e) o[e] = f2bf(bf2f(v[e])*sc + sh);
    *(u16x8*)&tl[di][lo] = o;
  }
  __syncthreads();
  #pragma unroll
  for (int j = 0; j < 2; ++j){
    const int li = (t>>3) + j*32, dof = (t&7)*8;
    u16x8 v;
    #pragma unroll
    for (int e = 0; e < 8; ++e) v[e] = tl[dof+e][li];
    *(u16x8*)(D + (long)(l0+li)*1024 + d0 + dof) = v;
  }
}

__global__ __launch_bounds__(256) void softmax_k(
    const float* __restrict__ S, u16* __restrict__ P)
{
  const long row = blockIdx.x;
  const float* p = S + row*1024;
  const int t = threadIdx.x;
  f4 v = *(const f4*)&p[t*4];
  v *= 0.03125f;
  float mx = fmaxf(fmaxf(v[0],v[1]), fmaxf(v[2],v[3]));
  #pragma unroll
  for (int o = 1; o < 64; o <<= 1) mx = fmaxf(mx, __shfl_xor(mx, o));
  __shared__ float red[4], red2[4];
  if ((t & 63) == 0) red[t>>6] = mx;
  __syncthreads();
  mx = fmaxf(fmaxf(red[0],red[1]), fmaxf(red[2],red[3]));
  f4 e;
  e[0]=__expf(v[0]-mx); e[1]=__expf(v[1]-mx); e[2]=__expf(v[2]-mx); e[3]=__expf(v[3]-mx);
  float sm = e[0]+e[1]+e[2]+e[3];
  #pragma unroll
  for (int o = 1; o < 64; o <<= 1) sm += __shfl_xor(sm, o);
  if ((t & 63) == 0) red2[t>>6] = sm;
  __syncthreads();
  sm = red2[0]+red2[1]+red2[2]+red2[3];
  const float inv = 1.0f/sm;
  u16x4 o4; o4[0]=f2bf(e[0]*inv); o4[1]=f2bf(e[1]*inv); o4[2]=f2bf(e[2]*inv); o4[3]=f2bf(e[3]*inv);
  *(u16x4*)&P[row*1024 + t*4] = o4;
}

// ---------------------------------------------------------------------------
extern "C" void kernel_launch(void* const* d_in, const int* in_sizes, int n_in,
                              void* d_out, int out_size, void* d_ws, size_t ws_size,
                              hipStream_t stream)
{
  const float* feat  = (const float*)d_in[0];
  const float* w_enc = (const float*)d_in[1];
  const float* b_enc = (const float*)d_in[2];
  const float* w_k   = (const float*)d_in[3];
  const float* b_k   = (const float*)d_in[4];
  const float* w_v   = (const float*)d_in[5];
  const float* b_v   = (const float*)d_in[6];
  const float* fcq_w = (const float*)d_in[7];
  // d_in[8] fcq_b, d_in[10] fck_b: cancelled exactly by train-mode BN.
  const float* fck_w = (const float*)d_in[9];
  const float* bnq_g = (const float*)d_in[11];
  const float* bnq_b = (const float*)d_in[12];
  const float* bnk_g = (const float*)d_in[13];
  const float* bnk_b = (const float*)d_in[14];
  const float* ff1w  = (const float*)d_in[15];
  const float* ff1b  = (const float*)d_in[16];
  const float* ff2w  = (const float*)d_in[17];
  const float* ff2b  = (const float*)d_in[18];

  char* ws = (char*)d_ws;
  u16*   Aq      = (u16*)  (ws);                   // [0,32)  MB [B][L][4096] (Ak follows)
  u16*   Ak      = (u16*)  (ws + (32ull<<20));     // [32,64)
  u16*   Vc      = (u16*)  (ws + (64ull<<20));     // [64,96)  [B][4096][L]
  u16*   Wq      = (u16*)  (ws + (96ull<<20));     // [96,104)  (Wk follows)
  u16*   Wk      = (u16*)  (ws + (104ull<<20));    // [104,112)
  u16*   q_bf    = (u16*)  (ws + (112ull<<20));    // [112,120) (k_bf follows)
  u16*   k_bf    = (u16*)  (ws + (120ull<<20));    // [120,128)
  u16*   qk_rawT = (u16*)  (ws + (128ull<<20));    // [128,144) bf16 pre-BN q|k C^T [z][d][l]
  float* scores  = (float*)(ws + (160ull<<20));    // [160,176)
  u16*   attn    = (u16*)  (ws + (176ull<<20));    // [176,184)
  u16*   out_nhwc= (u16*)  (ws + (184ull<<20));    // [184,216) [B][65536][64]
  u16*   NX      = (u16*)  (ws + (128ull<<20));    // [128,160) transient (dead before qk_rawT)
  u16*   Vl      = (u16*)  (ws + (160ull<<20));    // [160,192) transient (dead before scores)
  u16*   Wt2     = (u16*)  (ws + (216ull<<20));    // +221KB
  float* stats   = (float*)(ws + (217ull<<20));    // 32KB
  u16*   W1b     = (u16*)  (ws + (218ull<<20));    // 32KB [256][64] bf16
  u16*   W2b     = (u16*)  (ws + (218ull<<20) + 65536); // 32KB [64][256] bf16
  u16*   h1      = (u16*)  (ws);                   // [0,128) reuse (Aq..k_bf dead by ff1)

  hipMemsetAsync(stats, 0, 4096*sizeof(float), stream);

  to_nhwc<<<dim3(1024,4), 256, 0, stream>>>(feat, NX);
  wt_prep<<<dim3(432), 256, 0, stream>>>(w_enc, w_k, w_v, Wt2);
  conv_mfma<<<dim3(16,32,4), 512, 0, stream>>>(NX, Wt2, b_enc, b_k, b_v, Aq, Ak, Vl);
  v_tr<<<dim3(64,16,4), 256, 0, stream>>>(Vl, Vc);
  cvt_w<<<dim3(4096,2), 256, 0, stream>>>(fcq_w, fck_w, Wq, Wk);
  cvt_ffw<<<dim3(16,2), 256, 0, stream>>>(ff1w, ff2w, W1b, W2b);

  // merged q+k projections (z 0..3: q, 4..7: k), bf16 C^T + fused BN stats
  // grid (8,8,8) = 512 blocks: gxl=3, gyl=3, n8l=6
  gemm_bt128<2><<<dim3(8,8,8), 256, 0, stream>>>(Aq, 4194304, Wq, 4194304, 2,
                                                 qk_rawT, 1048576, 1024, 1024, 4096, stats,
                                                 3, 3, 6);

  bn_fin2<<<dim3(4,2), 256, 0, stream>>>(stats, bnq_g, bnq_b, bnk_g, bnk_b);
  bn_apply_t<<<dim3(16,16,8), 256, 0, stream>>>(qk_rawT, stats, q_bf);

  // QK: grid (8,8,4) = 256 blocks: gxl=3, gyl=3, n8l=5
  gemm_bt128<0><<<dim3(8,8,4), 256, 0, stream>>>(q_bf, 1048576, k_bf, 1048576, 0,
                                                 scores, 1048576, 1024, 1024, 1024, nullptr,
                                                 3, 3, 5);
  softmax_k<<<dim3(4096), 256, 0, stream>>>(scores, attn);

  // attn@V: grid (8,32,4) = 1024 blocks: gxl=3, gyl=5, n8l=7
  gemm_bt128<1><<<dim3(8,32,4), 256, 0, stream>>>(attn, 1048576, Vc, 4194304, 0,
                                                  out_nhwc, 0, 1024, 4096, 1024, nullptr,
                                                  3, 5, 7);

  ff1_mfma<<<dim3(2048,2), 256, 0, stream>>>(out_nhwc, W1b, ff1b, h1);
  ff2_mfma<<<dim3(1024), 256, 0, stream>>>(h1, W2b, ff2b, feat, (float*)d_out);
}

// Round 15
// 515.399 us; speedup vs baseline: 1.0576x; 1.0151x over previous
//
#include <hip/hip_runtime.h>

typedef unsigned short u16;
typedef float f4 __attribute__((ext_vector_type(4)));
typedef float f32x4 __attribute__((ext_vector_type(4)));
typedef short bf16x8 __attribute__((ext_vector_type(8)));
typedef u16 u16x8 __attribute__((ext_vector_type(8)));
typedef u16 u16x4 __attribute__((ext_vector_type(4)));

__device__ __forceinline__ u16 f2bf(float f){
  unsigned u = __float_as_uint(f);
  u = (u + 0x7FFFu + ((u>>16)&1u)) >> 16;
  return (u16)u;
}
__device__ __forceinline__ float bf2f(u16 u){
  return __uint_as_float(((unsigned)u)<<16);
}
// tanh-form GELU: max |dev| vs exact erf-GELU ~1e-3 (threshold is 0.108).
__device__ __forceinline__ float gelu_f(float x){
  float y = 1.5957691216057308f*(x + 0.044715f*x*x*x);
  y = fminf(y, 30.0f);
  float t = __expf(y);
  float r = __builtin_amdgcn_rcpf(t + 1.0f);
  return 0.5f*x*(1.0f + (t - 1.0f)*r);
}

// async global->LDS 16B (LDS dest is wave-uniform base + lane*16)
typedef __attribute__((address_space(1))) const unsigned int as1_cuint;
typedef __attribute__((address_space(3))) unsigned int as3_uint;
__device__ __forceinline__ void gload_lds16(const void* g, void* l){
  __builtin_amdgcn_global_load_lds((as1_cuint*)g, (as3_uint*)l, 16, 0, 0);
}

// ---------------------------------------------------------------------------
// feat NCHW fp32 -> NHWC bf16  ([4][256][256][64])
// ---------------------------------------------------------------------------
__global__ __launch_bounds__(256) void to_nhwc(
    const float* __restrict__ F, u16* __restrict__ O)
{
  __shared__ float tile[64][65];
  const int t = threadIdx.x, b = blockIdx.y;
  const long px0 = (long)blockIdx.x*64;
  const float* Fb = F + (long)b*64*65536;
  #pragma unroll
  for (int i = 0; i < 4; ++i){
    const int ch = (t>>4) + i*16;
    const int pxo = (t&15)*4;
    f4 v = *(const f4*)&Fb[(long)ch*65536 + px0 + pxo];
    tile[ch][pxo]=v[0]; tile[ch][pxo+1]=v[1]; tile[ch][pxo+2]=v[2]; tile[ch][pxo+3]=v[3];
  }
  __syncthreads();
  const int px = t & 63, ch0 = (t>>6)*16;
  u16x8 o0, o1;
  #pragma unroll
  for (int j = 0; j < 8; ++j){ o0[j]=f2bf(tile[ch0+j][px]); o1[j]=f2bf(tile[ch0+8+j][px]); }
  u16* Ob = O + ((long)b*65536 + px0 + px)*64 + ch0;
  *(u16x8*)Ob = o0; *(u16x8*)(Ob+8) = o1;
}

// ---------------------------------------------------------------------------
// conv weights -> Wt2[((dy*3+dx)*2+kc)*192 + n][32]  (fragment-contiguous bf16)
// ---------------------------------------------------------------------------
__global__ __launch_bounds__(256) void wt_prep(
    const float* __restrict__ we, const float* __restrict__ wk,
    const float* __restrict__ wv, u16* __restrict__ Wt2)
{
  const int i = blockIdx.x*256 + threadIdx.x;   // 110592 total
  const int cio = i & 31;
  const int t1 = i >> 5;
  const int n  = t1 % 192;
  const int t2 = t1 / 192;
  const int kc = t2 & 1, p = t2 >> 1;
  const int dy = p/3, dx = p - dy*3;
  const int ci = kc*32 + cio;
  const float* W = (n < 64) ? we : (n < 128) ? wk : wv;
  const int co = n & 63;
  Wt2[i] = f2bf(W[((co*64 + ci)*3 + dy)*3 + dx]);
}

// ---------------------------------------------------------------------------
// MFMA implicit-GEMM conv (512 thr, 2 blocks/CU, two-phase LDS epilogue).
// ---------------------------------------------------------------------------
__global__ __launch_bounds__(512,2) void conv_mfma(
    const u16* __restrict__ X, const u16* __restrict__ Wt2,
    const float* __restrict__ be, const float* __restrict__ bk, const float* __restrict__ bv,
    u16* __restrict__ Aq, u16* __restrict__ Ak, u16* __restrict__ Vl)
{
  __shared__ __align__(16) u16 smem[24576];   // 48KB: halo / epilogue reuse
  const int t = threadIdx.x, lane = t & 63, wvi = t >> 6;
  const int bx = blockIdx.x, by = blockIdx.y, b = blockIdx.z;
  const int x0 = bx*16, y0 = by*8;
  const u16* Xb = X + (long)b*4194304;

  #pragma unroll
  for (int j = 0; j < 3; ++j){
    const int id = t + j*512;
    if (id < 1440){
      const int row = id / 144, rem = id - row*144, col = rem >> 3, ck = rem & 7;
      const int y = y0 - 1 + row, x = x0 - 1 + col;
      int4 v = {0,0,0,0};
      if ((unsigned)y < 256u && (unsigned)x < 256u)
        v = *(const int4*)(Xb + ((long)y*256 + x)*64 + ck*8);
      *(int4*)&smem[((row*18 + col)*8 + (ck ^ (col&7)))*8] = v;
    }
  }
  __syncthreads();

  const int wm4 = (wvi>>2)*4;
  const int wn  = (wvi&3)*48;
  const int fr = lane & 15, fo = lane >> 4;
  f32x4 acc[4][3] = {};

  #pragma unroll
  for (int dy = 0; dy < 3; ++dy)
  #pragma unroll
  for (int dx = 0; dx < 3; ++dx){
    const int p = dy*3 + dx;
    #pragma unroll
    for (int kc = 0; kc < 2; ++kc){
      bf16x8 af[4], bfv[3];
      const u16* wp = Wt2 + ((long)(p*2 + kc)*192 + wn + fr)*32 + fo*8;
      #pragma unroll
      for (int ni = 0; ni < 3; ++ni)
        bfv[ni] = *(const bf16x8*)(wp + ni*16*32);
      #pragma unroll
      for (int mi = 0; mi < 4; ++mi){
        const int row = wm4 + mi + dy;
        const int col = fr + dx;
        af[mi] = *(const bf16x8*)&smem[((row*18 + col)*8 + ((kc*4+fo) ^ (col&7)))*8];
      }
      #pragma unroll
      for (int mi = 0; mi < 4; ++mi)
        #pragma unroll
        for (int ni = 0; ni < 3; ++ni)
          acc[mi][ni] = __builtin_amdgcn_mfma_f32_16x16x32_bf16(af[mi], bfv[ni], acc[mi][ni], 0, 0, 0);
    }
  }
  __syncthreads();

  // phase 1: bias+GELU, frags -> LDS
  const int c0 = fo*4;
  const int lloc = c0 >> 3, kw0 = c0 & 7;
  #pragma unroll
  for (int ni = 0; ni < 3; ++ni){
    const int n = wn + ni*16 + fr;
    const int mat = n >> 6, co = n & 63;
    const float bias = (mat==0) ? be[co] : (mat==1) ? bk[co] : bv[co];
    #pragma unroll
    for (int mi = 0; mi < 4; ++mi){
      const int r = wm4 + mi;
      u16x4 o;
      #pragma unroll
      for (int rg = 0; rg < 4; ++rg) o[rg] = f2bf(gelu_f(acc[mi][ni][rg] + bias));
      const int e = ((mat*2 + lloc)*64 + co)*64 + ((r*8 + kw0) ^ ((co&7)<<3));
      *(u16x4*)&smem[e] = o;
    }
  }
  __syncthreads();

  // phase 2: six contiguous 8KB rows, 16B/lane coalesced
  const int l_lo = by*32 + bx*2;
  const int co_r = t >> 3, sw = (t&7) ^ (co_r&7);
  const int eoff = co_r*64 + sw*8;
  #pragma unroll
  for (int i = 0; i < 6; ++i){
    const int mat = i >> 1, ll = i & 1;
    u16x8 v = *(const u16x8*)&smem[(mat*2 + ll)*4096 + eoff];
    u16* dst = (mat==0 ? Aq : mat==1 ? Ak : Vl)
             + ((long)b*1024 + l_lo + ll)*4096 + t*8;
    *(u16x8*)dst = v;
  }
}

// ---------------------------------------------------------------------------
// V transpose: [b][l=1024][ck=4096] -> [b][ck][l]
// ---------------------------------------------------------------------------
__global__ __launch_bounds__(256) void v_tr(
    const u16* __restrict__ S, u16* __restrict__ D)
{
  __shared__ u16 tl[64][72];
  const int t = threadIdx.x, b = blockIdx.z;
  const int ck0 = blockIdx.x*64, l0 = blockIdx.y*64;
  const u16* Sb = S + (long)b*4194304;
  u16* Db = D + (long)b*4194304;
  #pragma unroll
  for (int j = 0; j < 2; ++j){
    const int li = (t>>3) + j*32, cko = (t&7)*8;
    *(u16x8*)&tl[li][cko] = *(const u16x8*)(Sb + (long)(l0+li)*4096 + ck0 + cko);
  }
  __syncthreads();
  #pragma unroll
  for (int j = 0; j < 2; ++j){
    const int cki = (t>>3) + j*32, lo = (t&7)*8;
    u16x8 v;
    #pragma unroll
    for (int e = 0; e < 8; ++e) v[e] = tl[lo+e][cki];
    *(u16x8*)(Db + (long)(ck0+cki)*1024 + l0 + lo) = v;
  }
}

// ---------------------------------------------------------------------------
// XCD-aware bijective block swizzle (T1, m204).
// ---------------------------------------------------------------------------
__device__ __forceinline__ void xcd_map(int gxl, int gyl, int n8l,
                                        int& bx, int& by, int& bz){
  const int s = blockIdx.x + (blockIdx.y<<gxl) + (blockIdx.z<<(gxl+gyl));
  const int orig = ((s & 7) << n8l) + (s >> 3);
  bx = orig & ((1<<gxl)-1);
  by = (orig >> gxl) & ((1<<gyl)-1);
  bz = orig >> (gxl+gyl);
}

// ---------------------------------------------------------------------------
// attn@V GEMM (round-11 best config): 128x128 tile, BK=32, double-buffered
// 2x[128][32] LDS (32KB), one __syncthreads per K-step, __launch_bounds__(256,3),
// XCD swizzle, setprio. NHWC-fold bf16 epilogue.
// ---------------------------------------------------------------------------
__global__ __launch_bounds__(256,3) void gemm_av(
    const u16* __restrict__ A, long sA,
    const u16* __restrict__ B, long sB,
    void* __restrict__ Cv,
    const int M, const int N, const int K,
    const int gxl, const int gyl, const int n8l)
{
  int bx, by, bI;
  xcd_map(gxl, gyl, n8l, bx, by, bI);
  const u16* Ab = A + (long)bI*sA;
  const u16* Bb = B + (long)bI*sB;
  const int m0 = bx*128, n0 = by*128;
  __shared__ __align__(16) u16 As[8192];
  __shared__ __align__(16) u16 Bs[8192];
  const int t = threadIdx.x, lane = t & 63, wv = t >> 6;
  const int wm = (wv>>1)*64, wn = (wv&1)*64;
  const int fr = lane & 15, fo = lane >> 4;
  f32x4 acc[4][4] = {};
  const int c0 = wv*128 + lane, c1 = c0 + 64;
  const u16* Ag0 = Ab + (long)(m0 + (c0>>2))*K + (c0&3)*8;
  const u16* Ag1 = Ab + (long)(m0 + (c1>>2))*K + (c1&3)*8;
  const u16* Bg0 = Bb + (long)(n0 + (c0>>2))*K + (c0&3)*8;
  const u16* Bg1 = Bb + (long)(n0 + (c1>>2))*K + (c1&3)*8;
  const int lo0 = wv*1024;
  gload_lds16(Ag0, &As[lo0]);
  gload_lds16(Ag1, &As[lo0 + 512]);
  gload_lds16(Bg0, &Bs[lo0]);
  gload_lds16(Bg1, &Bs[lo0 + 512]);
  const int nk = K >> 5;
  int cur = 0;
  for (int ki = 0; ki < nk; ++ki){
    __syncthreads();
    if (ki + 1 < nk){
      const int k0 = (ki + 1) << 5;
      const int so = ((cur^1) << 12) + lo0;
      gload_lds16(Ag0 + k0, &As[so]);
      gload_lds16(Ag1 + k0, &As[so + 512]);
      gload_lds16(Bg0 + k0, &Bs[so]);
      gload_lds16(Bg1 + k0, &Bs[so + 512]);
    }
    const int ro = cur << 12;
    bf16x8 af[4], bfv[4];
    #pragma unroll
    for (int i = 0; i < 4; ++i){
      af[i]  = *(const bf16x8*)&As[ro + (wm + i*16 + fr)*32 + fo*8];
      bfv[i] = *(const bf16x8*)&Bs[ro + (wn + i*16 + fr)*32 + fo*8];
    }
    __builtin_amdgcn_s_setprio(1);
    #pragma unroll
    for (int mi = 0; mi < 4; ++mi)
      #pragma unroll
      for (int ni = 0; ni < 4; ++ni)
        acc[mi][ni] = __builtin_amdgcn_mfma_f32_16x16x32_bf16(af[mi], bfv[ni], acc[mi][ni], 0, 0, 0);
    __builtin_amdgcn_s_setprio(0);
    cur ^= 1;
  }
  // fold to NHWC: row=l=hb*32+wb, col=ck=c*64+kh*8+kw -> O[b][(hb*8+kh)*256+wb*8+kw][c]
  u16* O = (u16*)Cv;
  #pragma unroll
  for (int mi = 0; mi < 4; ++mi)
    #pragma unroll
    for (int ni = 0; ni < 4; ++ni){
      const int col = n0 + wn + ni*16 + fr;
      const int c = col >> 6, khh = (col>>3)&7, kww = col&7;
      #pragma unroll
      for (int r = 0; r < 4; ++r){
        const int row = m0 + wm + mi*16 + fo*4 + r;
        const int hb = row >> 5, wbb = row & 31;
        O[(((long)bI*65536 + (hb*8+khh)*256 + wbb*8 + kww)<<6) + c] = f2bf(acc[mi][ni][r]);
      }
    }
}

// ---------------------------------------------------------------------------
// proj/QK GEMM: 128x128 tile, BK=64 per barrier, 2-slot x 2-half dbuf (64KB).
// EPI 0: fp32 C. EPI 2: bf16 C^T [N][M] + fused BN stats.
// ---------------------------------------------------------------------------
template<int EPI>
__global__ __launch_bounds__(256,2) void gemm_bt128(
    const u16* __restrict__ A, long sA,
    const u16* __restrict__ B, long sB, const int zshB,
    void* __restrict__ Cv, long sC,
    const int M, const int N, const int K,
    float* __restrict__ bnstats,
    const int gxl, const int gyl, const int n8l)
{
  int bx, by, bI;
  xcd_map(gxl, gyl, n8l, bx, by, bI);
  const u16* Ab = A + (long)bI*sA;
  const u16* Bb = B + (long)(bI>>zshB)*sB;
  const int m0 = bx*128, n0 = by*128;
  __shared__ __align__(16) u16 As[16384];   // [2 slot][2 half][128][32]
  __shared__ __align__(16) u16 Bs[16384];
  const int t = threadIdx.x, lane = t & 63, wv = t >> 6;
  const int wm = (wv>>1)*64, wn = (wv&1)*64;
  const int fr = lane & 15, fo = lane >> 4;
  f32x4 acc[4][4] = {};
  const int c0 = wv*128 + lane, c1 = c0 + 64;
  const u16* Ag0 = Ab + (long)(m0 + (c0>>2))*K + (c0&3)*8;
  const u16* Ag1 = Ab + (long)(m0 + (c1>>2))*K + (c1&3)*8;
  const u16* Bg0 = Bb + (long)(n0 + (c0>>2))*K + (c0&3)*8;
  const u16* Bg1 = Bb + (long)(n0 + (c1>>2))*K + (c1&3)*8;
#define STAGEH(slot, h, kofs) { \
    u16* a_ = &As[(((slot)*2+(h))<<12) + wv*1024]; \
    u16* b_ = &Bs[(((slot)*2+(h))<<12) + wv*1024]; \
    const int ko_ = (kofs) + 32*(h); \
    gload_lds16(Ag0 + ko_, a_); \
    gload_lds16(Ag1 + ko_, a_ + 512); \
    gload_lds16(Bg0 + ko_, b_); \
    gload_lds16(Bg1 + ko_, b_ + 512); }
  STAGEH(0, 0, 0)
  STAGEH(0, 1, 0)
  const int nk = K >> 6;
  int cur = 0;
  for (int ki = 0; ki < nk; ++ki){
    __syncthreads();
    if (ki + 1 < nk){
      const int k0 = (ki + 1) << 6;
      STAGEH(cur^1, 0, k0)
      STAGEH(cur^1, 1, k0)
    }
    #pragma unroll
    for (int h = 0; h < 2; ++h){
      const int ro = ((cur*2 + h) << 12);
      bf16x8 af[4], bfv[4];
      #pragma unroll
      for (int i = 0; i < 4; ++i){
        af[i]  = *(const bf16x8*)&As[ro + (wm + i*16 + fr)*32 + fo*8];
        bfv[i] = *(const bf16x8*)&Bs[ro + (wn + i*16 + fr)*32 + fo*8];
      }
      __builtin_amdgcn_s_setprio(1);
      #pragma unroll
      for (int mi = 0; mi < 4; ++mi)
        #pragma unroll
        for (int ni = 0; ni < 4; ++ni)
          acc[mi][ni] = __builtin_amdgcn_mfma_f32_16x16x32_bf16(af[mi], bfv[ni], acc[mi][ni], 0, 0, 0);
      __builtin_amdgcn_s_setprio(0);
    }
    cur ^= 1;
  }
#undef STAGEH
  if (EPI == 0){
    float* Cf = (float*)Cv + (long)bI*sC;
    #pragma unroll
    for (int mi = 0; mi < 4; ++mi)
      #pragma unroll
      for (int ni = 0; ni < 4; ++ni){
        const int col = n0 + wn + ni*16 + fr;
        #pragma unroll
        for (int r = 0; r < 4; ++r){
          const int row = m0 + wm + mi*16 + fo*4 + r;
          Cf[(long)row*N + col] = acc[mi][ni][r];
        }
      }
  } else {
    // bf16 C^T [N][M] + fused BN stats
    u16* Cb = (u16*)Cv + (long)bI*sC;
    #pragma unroll
    for (int mi = 0; mi < 4; ++mi)
      #pragma unroll
      for (int ni = 0; ni < 4; ++ni){
        const int col = n0 + wn + ni*16 + fr;
        const int row0 = m0 + wm + mi*16 + fo*4;
        u16x4 o;
        #pragma unroll
        for (int r = 0; r < 4; ++r) o[r] = f2bf(acc[mi][ni][r]);
        *(u16x4*)&Cb[(long)col*M + row0] = o;
      }
    const int sel = bI >> 2;
    float* sums = bnstats + sel*2048;
    #pragma unroll
    for (int ni = 0; ni < 4; ++ni){
      float s = 0.f, q = 0.f;
      #pragma unroll
      for (int mi = 0; mi < 4; ++mi)
        #pragma unroll
        for (int r = 0; r < 4; ++r){
          const float v = acc[mi][ni][r];
          s += v; q += v*v;
        }
      s += __shfl_xor(s, 16); s += __shfl_xor(s, 32);
      q += __shfl_xor(q, 16); q += __shfl_xor(q, 32);
      if (fo == 0){
        const int col = n0 + wn + ni*16 + fr;
        atomicAdd(&sums[col], s);
        atomicAdd(&sums[1024 + col], q);
      }
    }
  }
}

// ---------------------------------------------------------------------------
// ff1: C[262144][256] = X[262144][64] * W1b^T, bias+GELU, bf16 out. No LDS.
// ---------------------------------------------------------------------------
__global__ __launch_bounds__(256,3) void ff1_mfma(
    const u16* __restrict__ X, const u16* __restrict__ W1b,
    const float* __restrict__ B1, u16* __restrict__ H1)
{
  const int t = threadIdx.x, lane = t & 63, wv = t >> 6;
  const long m0 = (long)blockIdx.x*128 + (wv>>1)*64;
  const int n0 = blockIdx.y*128 + (wv&1)*64;
  const int fr = lane & 15, fo = lane >> 4;
  f32x4 acc[4][4] = {};
  #pragma unroll
  for (int k0 = 0; k0 < 64; k0 += 32){
    bf16x8 af[4], bfv[4];
    #pragma unroll
    for (int i = 0; i < 4; ++i){
      af[i]  = *(const bf16x8*)(X   + (m0 + i*16 + fr)*64 + k0 + fo*8);
      bfv[i] = *(const bf16x8*)(W1b + (long)(n0 + i*16 + fr)*64 + k0 + fo*8);
    }
    #pragma unroll
    for (int mi = 0; mi < 4; ++mi)
      #pragma unroll
      for (int ni = 0; ni < 4; ++ni)
        acc[mi][ni] = __builtin_amdgcn_mfma_f32_16x16x32_bf16(af[mi], bfv[ni], acc[mi][ni], 0, 0, 0);
  }
  #pragma unroll
  for (int ni = 0; ni < 4; ++ni){
    const int col = n0 + ni*16 + fr;
    const float bc = B1[col];
    #pragma unroll
    for (int mi = 0; mi < 4; ++mi){
      const long row = m0 + mi*16 + fo*4;
      #pragma unroll
      for (int r = 0; r < 4; ++r)
        H1[(row + r)*256 + col] = f2bf(gelu_f(acc[mi][ni][r] + bc));
    }
  }
}

// ---------------------------------------------------------------------------
// ff2: C[262144][64] = H1[262144][256] * W2b^T, bias+GELU+residual, fp32 NCHW.
// ---------------------------------------------------------------------------
__global__ __launch_bounds__(256,3) void ff2_mfma(
    const u16* __restrict__ H1, const u16* __restrict__ W2b,
    const float* __restrict__ B2, const float* __restrict__ F,
    float* __restrict__ OUT)
{
  const int t = threadIdx.x, lane = t & 63, wv = t >> 6;
  const long m0 = (long)blockIdx.x*256 + wv*64;
  const int fr = lane & 15, fo = lane >> 4;
  f32x4 acc[4][4] = {};
  for (int k0 = 0; k0 < 256; k0 += 32){
    bf16x8 af[4], bfv[4];
    #pragma unroll
    for (int i = 0; i < 4; ++i){
      af[i]  = *(const bf16x8*)(H1  + (m0 + i*16 + fr)*256 + k0 + fo*8);
      bfv[i] = *(const bf16x8*)(W2b + (long)(i*16 + fr)*256 + k0 + fo*8);
    }
    #pragma unroll
    for (int mi = 0; mi < 4; ++mi)
      #pragma unroll
      for (int ni = 0; ni < 4; ++ni)
        acc[mi][ni] = __builtin_amdgcn_mfma_f32_16x16x32_bf16(af[mi], bfv[ni], acc[mi][ni], 0, 0, 0);
  }
  #pragma unroll
  for (int ni = 0; ni < 4; ++ni){
    const int c = ni*16 + fr;
    const float bc = B2[c];
    #pragma unroll
    for (int mi = 0; mi < 4; ++mi){
      const long p = m0 + mi*16 + fo*4;
      const int b = (int)(p >> 16), pp = (int)(p & 65535);
      const long idx = ((long)(b*64 + c))*65536 + pp;
      const f4 fres = *(const f4*)&F[idx];
      f4 o;
      #pragma unroll
      for (int r = 0; r < 4; ++r) o[r] = gelu_f(acc[mi][ni][r] + bc) + fres[r];
      *(f4*)&OUT[idx] = o;
    }
  }
}

// ---------------------------------------------------------------------------
__global__ __launch_bounds__(256) void cvt_w(
    const float* __restrict__ Wq, const float* __restrict__ Wk,
    u16* __restrict__ Oq, u16* __restrict__ Ok)
{
  const long i = ((long)blockIdx.x*256 + threadIdx.x)*4;
  const float* s = blockIdx.y ? Wk : Wq;
  u16* d = blockIdx.y ? Ok : Oq;
  f4 v = *(const f4*)&s[i];
  u16x4 o; o[0]=f2bf(v[0]); o[1]=f2bf(v[1]); o[2]=f2bf(v[2]); o[3]=f2bf(v[3]);
  *(u16x4*)&d[i] = o;
}

__global__ __launch_bounds__(256) void cvt_ffw(
    const float* __restrict__ W1, const float* __restrict__ W2,
    u16* __restrict__ O1, u16* __restrict__ O2)
{
  const long i = ((long)blockIdx.x*256 + threadIdx.x)*4;
  const float* s = blockIdx.y ? W2 : W1;
  u16* d = blockIdx.y ? O2 : O1;
  f4 v = *(const f4*)&s[i];
  u16x4 o; o[0]=f2bf(v[0]); o[1]=f2bf(v[1]); o[2]=f2bf(v[2]); o[3]=f2bf(v[3]);
  *(u16x4*)&d[i] = o;
}

// ---------------------------------------------------------------------------
// BN finalize (stats from fused GEMM epilogue).
// ---------------------------------------------------------------------------
__global__ void bn_fin2(float* __restrict__ stats,
                        const float* __restrict__ gq, const float* __restrict__ bq,
                        const float* __restrict__ gk, const float* __restrict__ bk)
{
  const int sel = blockIdx.y;
  const int d = blockIdx.x*256 + threadIdx.x;
  if (d >= 1024) return;
  const float* sum   = stats + sel*2048;
  const float* sumsq = sum + 1024;
  const float* g    = sel ? gk : gq;
  const float* beta = sel ? bk : bq;
  const float m  = sum[d]   * (1.f/4096.f);
  const float vv = sumsq[d] * (1.f/4096.f) - m*m;
  const float sc = g[d] * rsqrtf(vv + 1e-5f);
  stats[4096 + sel*2048 + d]        = sc;
  stats[4096 + sel*2048 + 1024 + d] = beta[d] - m*sc;
}

// ---------------------------------------------------------------------------
// BN apply + transpose: QT [z][d=1024][l=1024] bf16 -> Y [z][l][d] bf16.
// ---------------------------------------------------------------------------
__global__ __launch_bounds__(256) void bn_apply_t(
    const u16* __restrict__ QT, const float* __restrict__ stats,
    u16* __restrict__ Y)
{
  __shared__ u16 tl[64][72];
  const int t = threadIdx.x, zi = blockIdx.z;
  const int d0 = blockIdx.x*64, l0 = blockIdx.y*64;
  const int sel = zi >> 2;
  const u16* S = QT + (long)zi*1048576;
  u16* D = Y + (long)zi*1048576;
  const float* scp = stats + 4096 + sel*2048;
  const float* shp = scp + 1024;
  #pragma unroll
  for (int j = 0; j < 2; ++j){
    const int di = (t>>3) + j*32, lo = (t&7)*8;
    const int d = d0 + di;
    const float sc = scp[d], sh = shp[d];
    u16x8 v = *(const u16x8*)(S + (long)d*1024 + l0 + lo);
    u16x8 o;
    #pragma unroll
    for (int e = 0; e < 8; ++e) o[e] = f2bf(bf2f(v[e])*sc + sh);
    *(u16x8*)&tl[di][lo] = o;
  }
  __syncthreads();
  #pragma unroll
  for (int j = 0; j < 2; ++j){
    const int li = (t>>3) + j*32, dof = (t&7)*8;
    u16x8 v;
    #pragma unroll
    for (int e = 0; e < 8; ++e) v[e] = tl[dof+e][li];
    *(u16x8*)(D + (long)(l0+li)*1024 + d0 + dof) = v;
  }
}

__global__ __launch_bounds__(256) void softmax_k(
    const float* __restrict__ S, u16* __restrict__ P)
{
  const long row = blockIdx.x;
  const float* p = S + row*1024;
  const int t = threadIdx.x;
  f4 v = *(const f4*)&p[t*4];
  v *= 0.03125f;
  float mx = fmaxf(fmaxf(v[0],v[1]), fmaxf(v[2],v[3]));
  #pragma unroll
  for (int o = 1; o < 64; o <<= 1) mx = fmaxf(mx, __shfl_xor(mx, o));
  __shared__ float red[4], red2[4];
  if ((t & 63) == 0) red[t>>6] = mx;
  __syncthreads();
  mx = fmaxf(fmaxf(red[0],red[1]), fmaxf(red[2],red[3]));
  f4 e;
  e[0]=__expf(v[0]-mx); e[1]=__expf(v[1]-mx); e[2]=__expf(v[2]-mx); e[3]=__expf(v[3]-mx);
  float sm = e[0]+e[1]+e[2]+e[3];
  #pragma unroll
  for (int o = 1; o < 64; o <<= 1) sm += __shfl_xor(sm, o);
  if ((t & 63) == 0) red2[t>>6] = sm;
  __syncthreads();
  sm = red2[0]+red2[1]+red2[2]+red2[3];
  const float inv = 1.0f/sm;
  u16x4 o4; o4[0]=f2bf(e[0]*inv); o4[1]=f2bf(e[1]*inv); o4[2]=f2bf(e[2]*inv); o4[3]=f2bf(e[3]*inv);
  *(u16x4*)&P[row*1024 + t*4] = o4;
}

// ---------------------------------------------------------------------------
extern "C" void kernel_launch(void* const* d_in, const int* in_sizes, int n_in,
                              void* d_out, int out_size, void* d_ws, size_t ws_size,
                              hipStream_t stream)
{
  const float* feat  = (const float*)d_in[0];
  const float* w_enc = (const float*)d_in[1];
  const float* b_enc = (const float*)d_in[2];
  const float* w_k   = (const float*)d_in[3];
  const float* b_k   = (const float*)d_in[4];
  const float* w_v   = (const float*)d_in[5];
  const float* b_v   = (const float*)d_in[6];
  const float* fcq_w = (const float*)d_in[7];
  // d_in[8] fcq_b, d_in[10] fck_b: cancelled exactly by train-mode BN.
  const float* fck_w = (const float*)d_in[9];
  const float* bnq_g = (const float*)d_in[11];
  const float* bnq_b = (const float*)d_in[12];
  const float* bnk_g = (const float*)d_in[13];
  const float* bnk_b = (const float*)d_in[14];
  const float* ff1w  = (const float*)d_in[15];
  const float* ff1b  = (const float*)d_in[16];
  const float* ff2w  = (const float*)d_in[17];
  const float* ff2b  = (const float*)d_in[18];

  char* ws = (char*)d_ws;
  u16*   Aq      = (u16*)  (ws);                   // [0,32)  MB [B][L][4096] (Ak follows)
  u16*   Ak      = (u16*)  (ws + (32ull<<20));     // [32,64)
  u16*   Vc      = (u16*)  (ws + (64ull<<20));     // [64,96)  [B][4096][L]
  u16*   Wq      = (u16*)  (ws + (96ull<<20));     // [96,104)  (Wk follows)
  u16*   Wk      = (u16*)  (ws + (104ull<<20));    // [104,112)
  u16*   q_bf    = (u16*)  (ws + (112ull<<20));    // [112,120) (k_bf follows)
  u16*   k_bf    = (u16*)  (ws + (120ull<<20));    // [120,128)
  u16*   qk_rawT = (u16*)  (ws + (128ull<<20));    // [128,144) bf16 pre-BN q|k C^T [z][d][l]
  float* scores  = (float*)(ws + (160ull<<20));    // [160,176)
  u16*   attn    = (u16*)  (ws + (176ull<<20));    // [176,184)
  u16*   out_nhwc= (u16*)  (ws + (184ull<<20));    // [184,216) [B][65536][64]
  u16*   NX      = (u16*)  (ws + (128ull<<20));    // [128,160) transient (dead before qk_rawT)
  u16*   Vl      = (u16*)  (ws + (160ull<<20));    // [160,192) transient (dead before scores)
  u16*   Wt2     = (u16*)  (ws + (216ull<<20));    // +221KB
  float* stats   = (float*)(ws + (217ull<<20));    // 32KB
  u16*   W1b     = (u16*)  (ws + (218ull<<20));    // 32KB [256][64] bf16
  u16*   W2b     = (u16*)  (ws + (218ull<<20) + 65536); // 32KB [64][256] bf16
  u16*   h1      = (u16*)  (ws);                   // [0,128) reuse (Aq..k_bf dead by ff1)

  hipMemsetAsync(stats, 0, 4096*sizeof(float), stream);

  to_nhwc<<<dim3(1024,4), 256, 0, stream>>>(feat, NX);
  wt_prep<<<dim3(432), 256, 0, stream>>>(w_enc, w_k, w_v, Wt2);
  conv_mfma<<<dim3(16,32,4), 512, 0, stream>>>(NX, Wt2, b_enc, b_k, b_v, Aq, Ak, Vl);
  v_tr<<<dim3(64,16,4), 256, 0, stream>>>(Vl, Vc);
  cvt_w<<<dim3(4096,2), 256, 0, stream>>>(fcq_w, fck_w, Wq, Wk);
  cvt_ffw<<<dim3(16,2), 256, 0, stream>>>(ff1w, ff2w, W1b, W2b);

  // merged q+k projections (z 0..3: q, 4..7: k), bf16 C^T + fused BN stats
  // grid (8,8,8) = 512 blocks: gxl=3, gyl=3, n8l=6
  gemm_bt128<2><<<dim3(8,8,8), 256, 0, stream>>>(Aq, 4194304, Wq, 4194304, 2,
                                                 qk_rawT, 1048576, 1024, 1024, 4096, stats,
                                                 3, 3, 6);

  bn_fin2<<<dim3(4,2), 256, 0, stream>>>(stats, bnq_g, bnq_b, bnk_g, bnk_b);
  bn_apply_t<<<dim3(16,16,8), 256, 0, stream>>>(qk_rawT, stats, q_bf);

  // QK: grid (8,8,4) = 256 blocks: gxl=3, gyl=3, n8l=5
  gemm_bt128<0><<<dim3(8,8,4), 256, 0, stream>>>(q_bf, 1048576, k_bf, 1048576, 0,
                                                 scores, 1048576, 1024, 1024, 1024, nullptr,
                                                 3, 3, 5);
  softmax_k<<<dim3(4096), 256, 0, stream>>>(scores, attn);

  // attn@V: grid (8,32,4) = 1024 blocks: gxl=3, gyl=5, n8l=7 (round-11 config)
  gemm_av<<<dim3(8,32,4), 256, 0, stream>>>(attn, 1048576, Vc, 4194304,
                                            out_nhwc, 1024, 4096, 1024,
                                            3, 5, 7);

  ff1_mfma<<<dim3(2048,2), 256, 0, stream>>>(out_nhwc, W1b, ff1b, h1);
  ff2_mfma<<<dim3(1024), 256, 0, stream>>>(h1, W2b, ff2b, feat, (float*)d_out);
}

// Round 16
// 477.931 us; speedup vs baseline: 1.1405x; 1.0784x over previous
//
#include <hip/hip_runtime.h>

typedef unsigned short u16;
typedef float f4 __attribute__((ext_vector_type(4)));
typedef float f32x4 __attribute__((ext_vector_type(4)));
typedef short bf16x8 __attribute__((ext_vector_type(8)));
typedef u16 u16x8 __attribute__((ext_vector_type(8)));
typedef u16 u16x4 __attribute__((ext_vector_type(4)));

__device__ __forceinline__ u16 f2bf(float f){
  unsigned u = __float_as_uint(f);
  u = (u + 0x7FFFu + ((u>>16)&1u)) >> 16;
  return (u16)u;
}
__device__ __forceinline__ float bf2f(u16 u){
  return __uint_as_float(((unsigned)u)<<16);
}
// tanh-form GELU: max |dev| vs exact erf-GELU ~1e-3 (threshold is 0.108).
__device__ __forceinline__ float gelu_f(float x){
  float y = 1.5957691216057308f*(x + 0.044715f*x*x*x);
  y = fminf(y, 30.0f);
  float t = __expf(y);
  float r = __builtin_amdgcn_rcpf(t + 1.0f);
  return 0.5f*x*(1.0f + (t - 1.0f)*r);
}

// async global->LDS 16B (LDS dest is wave-uniform base + lane*16)
typedef __attribute__((address_space(1))) const unsigned int as1_cuint;
typedef __attribute__((address_space(3))) unsigned int as3_uint;
__device__ __forceinline__ void gload_lds16(const void* g, void* l){
  __builtin_amdgcn_global_load_lds((as1_cuint*)g, (as3_uint*)l, 16, 0, 0);
}

// ---------------------------------------------------------------------------
// feat NCHW fp32 -> NHWC bf16  ([4][256][256][64])
// ---------------------------------------------------------------------------
__global__ __launch_bounds__(256) void to_nhwc(
    const float* __restrict__ F, u16* __restrict__ O)
{
  __shared__ float tile[64][65];
  const int t = threadIdx.x, b = blockIdx.y;
  const long px0 = (long)blockIdx.x*64;
  const float* Fb = F + (long)b*64*65536;
  #pragma unroll
  for (int i = 0; i < 4; ++i){
    const int ch = (t>>4) + i*16;
    const int pxo = (t&15)*4;
    f4 v = *(const f4*)&Fb[(long)ch*65536 + px0 + pxo];
    tile[ch][pxo]=v[0]; tile[ch][pxo+1]=v[1]; tile[ch][pxo+2]=v[2]; tile[ch][pxo+3]=v[3];
  }
  __syncthreads();
  const int px = t & 63, ch0 = (t>>6)*16;
  u16x8 o0, o1;
  #pragma unroll
  for (int j = 0; j < 8; ++j){ o0[j]=f2bf(tile[ch0+j][px]); o1[j]=f2bf(tile[ch0+8+j][px]); }
  u16* Ob = O + ((long)b*65536 + px0 + px)*64 + ch0;
  *(u16x8*)Ob = o0; *(u16x8*)(Ob+8) = o1;
}

// ---------------------------------------------------------------------------
// conv weights -> Wt2[((dy*3+dx)*2+kc)*192 + n][32]  (fragment-contiguous bf16)
// ---------------------------------------------------------------------------
__global__ __launch_bounds__(256) void wt_prep(
    const float* __restrict__ we, const float* __restrict__ wk,
    const float* __restrict__ wv, u16* __restrict__ Wt2)
{
  const int i = blockIdx.x*256 + threadIdx.x;   // 110592 total
  const int cio = i & 31;
  const int t1 = i >> 5;
  const int n  = t1 % 192;
  const int t2 = t1 / 192;
  const int kc = t2 & 1, p = t2 >> 1;
  const int dy = p/3, dx = p - dy*3;
  const int ci = kc*32 + cio;
  const float* W = (n < 64) ? we : (n < 128) ? wk : wv;
  const int co = n & 63;
  Wt2[i] = f2bf(W[((co*64 + ci)*3 + dy)*3 + dx]);
}

// ---------------------------------------------------------------------------
// MFMA implicit-GEMM conv (512 thr, 2 blocks/CU, two-phase LDS epilogue).
// ---------------------------------------------------------------------------
__global__ __launch_bounds__(512,2) void conv_mfma(
    const u16* __restrict__ X, const u16* __restrict__ Wt2,
    const float* __restrict__ be, const float* __restrict__ bk, const float* __restrict__ bv,
    u16* __restrict__ Aq, u16* __restrict__ Ak, u16* __restrict__ Vl)
{
  __shared__ __align__(16) u16 smem[24576];   // 48KB: halo / epilogue reuse
  const int t = threadIdx.x, lane = t & 63, wvi = t >> 6;
  const int bx = blockIdx.x, by = blockIdx.y, b = blockIdx.z;
  const int x0 = bx*16, y0 = by*8;
  const u16* Xb = X + (long)b*4194304;

  #pragma unroll
  for (int j = 0; j < 3; ++j){
    const int id = t + j*512;
    if (id < 1440){
      const int row = id / 144, rem = id - row*144, col = rem >> 3, ck = rem & 7;
      const int y = y0 - 1 + row, x = x0 - 1 + col;
      int4 v = {0,0,0,0};
      if ((unsigned)y < 256u && (unsigned)x < 256u)
        v = *(const int4*)(Xb + ((long)y*256 + x)*64 + ck*8);
      *(int4*)&smem[((row*18 + col)*8 + (ck ^ (col&7)))*8] = v;
    }
  }
  __syncthreads();

  const int wm4 = (wvi>>2)*4;
  const int wn  = (wvi&3)*48;
  const int fr = lane & 15, fo = lane >> 4;
  f32x4 acc[4][3] = {};

  #pragma unroll
  for (int dy = 0; dy < 3; ++dy)
  #pragma unroll
  for (int dx = 0; dx < 3; ++dx){
    const int p = dy*3 + dx;
    #pragma unroll
    for (int kc = 0; kc < 2; ++kc){
      bf16x8 af[4], bfv[3];
      const u16* wp = Wt2 + ((long)(p*2 + kc)*192 + wn + fr)*32 + fo*8;
      #pragma unroll
      for (int ni = 0; ni < 3; ++ni)
        bfv[ni] = *(const bf16x8*)(wp + ni*16*32);
      #pragma unroll
      for (int mi = 0; mi < 4; ++mi){
        const int row = wm4 + mi + dy;
        const int col = fr + dx;
        af[mi] = *(const bf16x8*)&smem[((row*18 + col)*8 + ((kc*4+fo) ^ (col&7)))*8];
      }
      #pragma unroll
      for (int mi = 0; mi < 4; ++mi)
        #pragma unroll
        for (int ni = 0; ni < 3; ++ni)
          acc[mi][ni] = __builtin_amdgcn_mfma_f32_16x16x32_bf16(af[mi], bfv[ni], acc[mi][ni], 0, 0, 0);
    }
  }
  __syncthreads();

  // phase 1: bias+GELU, frags -> LDS
  const int c0 = fo*4;
  const int lloc = c0 >> 3, kw0 = c0 & 7;
  #pragma unroll
  for (int ni = 0; ni < 3; ++ni){
    const int n = wn + ni*16 + fr;
    const int mat = n >> 6, co = n & 63;
    const float bias = (mat==0) ? be[co] : (mat==1) ? bk[co] : bv[co];
    #pragma unroll
    for (int mi = 0; mi < 4; ++mi){
      const int r = wm4 + mi;
      u16x4 o;
      #pragma unroll
      for (int rg = 0; rg < 4; ++rg) o[rg] = f2bf(gelu_f(acc[mi][ni][rg] + bias));
      const int e = ((mat*2 + lloc)*64 + co)*64 + ((r*8 + kw0) ^ ((co&7)<<3));
      *(u16x4*)&smem[e] = o;
    }
  }
  __syncthreads();

  // phase 2: six contiguous 8KB rows, 16B/lane coalesced
  const int l_lo = by*32 + bx*2;
  const int co_r = t >> 3, sw = (t&7) ^ (co_r&7);
  const int eoff = co_r*64 + sw*8;
  #pragma unroll
  for (int i = 0; i < 6; ++i){
    const int mat = i >> 1, ll = i & 1;
    u16x8 v = *(const u16x8*)&smem[(mat*2 + ll)*4096 + eoff];
    u16* dst = (mat==0 ? Aq : mat==1 ? Ak : Vl)
             + ((long)b*1024 + l_lo + ll)*4096 + t*8;
    *(u16x8*)dst = v;
  }
}

// ---------------------------------------------------------------------------
// V transpose: [b][l=1024][ck=4096] -> [b][ck][l]
// ---------------------------------------------------------------------------
__global__ __launch_bounds__(256) void v_tr(
    const u16* __restrict__ S, u16* __restrict__ D)
{
  __shared__ u16 tl[64][72];
  const int t = threadIdx.x, b = blockIdx.z;
  const int ck0 = blockIdx.x*64, l0 = blockIdx.y*64;
  const u16* Sb = S + (long)b*4194304;
  u16* Db = D + (long)b*4194304;
  #pragma unroll
  for (int j = 0; j < 2; ++j){
    const int li = (t>>3) + j*32, cko = (t&7)*8;
    *(u16x8*)&tl[li][cko] = *(const u16x8*)(Sb + (long)(l0+li)*4096 + ck0 + cko);
  }
  __syncthreads();
  #pragma unroll
  for (int j = 0; j < 2; ++j){
    const int cki = (t>>3) + j*32, lo = (t&7)*8;
    u16x8 v;
    #pragma unroll
    for (int e = 0; e < 8; ++e) v[e] = tl[lo+e][cki];
    *(u16x8*)(Db + (long)(ck0+cki)*1024 + l0 + lo) = v;
  }
}

// ---------------------------------------------------------------------------
// XCD-aware bijective block swizzle (T1, m204).
// ---------------------------------------------------------------------------
__device__ __forceinline__ void xcd_map(int gxl, int gyl, int n8l,
                                        int& bx, int& by, int& bz){
  const int s = blockIdx.x + (blockIdx.y<<gxl) + (blockIdx.z<<(gxl+gyl));
  const int orig = ((s & 7) << n8l) + (s >> 3);
  bx = orig & ((1<<gxl)-1);
  by = (orig >> gxl) & ((1<<gyl)-1);
  bz = orig >> (gxl+gyl);
}

// ---------------------------------------------------------------------------
// attn@V GEMM (round-11 best config): 128x128 tile, BK=32, double-buffered,
// one __syncthreads per K-step, (256,3), XCD swizzle, setprio, NHWC fold.
// ---------------------------------------------------------------------------
__global__ __launch_bounds__(256,3) void gemm_av(
    const u16* __restrict__ A, long sA,
    const u16* __restrict__ B, long sB,
    void* __restrict__ Cv,
    const int M, const int N, const int K,
    const int gxl, const int gyl, const int n8l)
{
  int bx, by, bI;
  xcd_map(gxl, gyl, n8l, bx, by, bI);
  const u16* Ab = A + (long)bI*sA;
  const u16* Bb = B + (long)bI*sB;
  const int m0 = bx*128, n0 = by*128;
  __shared__ __align__(16) u16 As[8192];
  __shared__ __align__(16) u16 Bs[8192];
  const int t = threadIdx.x, lane = t & 63, wv = t >> 6;
  const int wm = (wv>>1)*64, wn = (wv&1)*64;
  const int fr = lane & 15, fo = lane >> 4;
  f32x4 acc[4][4] = {};
  const int c0 = wv*128 + lane, c1 = c0 + 64;
  const u16* Ag0 = Ab + (long)(m0 + (c0>>2))*K + (c0&3)*8;
  const u16* Ag1 = Ab + (long)(m0 + (c1>>2))*K + (c1&3)*8;
  const u16* Bg0 = Bb + (long)(n0 + (c0>>2))*K + (c0&3)*8;
  const u16* Bg1 = Bb + (long)(n0 + (c1>>2))*K + (c1&3)*8;
  const int lo0 = wv*1024;
  gload_lds16(Ag0, &As[lo0]);
  gload_lds16(Ag1, &As[lo0 + 512]);
  gload_lds16(Bg0, &Bs[lo0]);
  gload_lds16(Bg1, &Bs[lo0 + 512]);
  const int nk = K >> 5;
  int cur = 0;
  for (int ki = 0; ki < nk; ++ki){
    __syncthreads();
    if (ki + 1 < nk){
      const int k0 = (ki + 1) << 5;
      const int so = ((cur^1) << 12) + lo0;
      gload_lds16(Ag0 + k0, &As[so]);
      gload_lds16(Ag1 + k0, &As[so + 512]);
      gload_lds16(Bg0 + k0, &Bs[so]);
      gload_lds16(Bg1 + k0, &Bs[so + 512]);
    }
    const int ro = cur << 12;
    bf16x8 af[4], bfv[4];
    #pragma unroll
    for (int i = 0; i < 4; ++i){
      af[i]  = *(const bf16x8*)&As[ro + (wm + i*16 + fr)*32 + fo*8];
      bfv[i] = *(const bf16x8*)&Bs[ro + (wn + i*16 + fr)*32 + fo*8];
    }
    __builtin_amdgcn_s_setprio(1);
    #pragma unroll
    for (int mi = 0; mi < 4; ++mi)
      #pragma unroll
      for (int ni = 0; ni < 4; ++ni)
        acc[mi][ni] = __builtin_amdgcn_mfma_f32_16x16x32_bf16(af[mi], bfv[ni], acc[mi][ni], 0, 0, 0);
    __builtin_amdgcn_s_setprio(0);
    cur ^= 1;
  }
  // fold to NHWC: row=l=hb*32+wb, col=ck=c*64+kh*8+kw -> O[b][(hb*8+kh)*256+wb*8+kw][c]
  u16* O = (u16*)Cv;
  #pragma unroll
  for (int mi = 0; mi < 4; ++mi)
    #pragma unroll
    for (int ni = 0; ni < 4; ++ni){
      const int col = n0 + wn + ni*16 + fr;
      const int c = col >> 6, khh = (col>>3)&7, kww = col&7;
      #pragma unroll
      for (int r = 0; r < 4; ++r){
        const int row = m0 + wm + mi*16 + fo*4 + r;
        const int hb = row >> 5, wbb = row & 31;
        O[(((long)bI*65536 + (hb*8+khh)*256 + wbb*8 + kww)<<6) + c] = f2bf(acc[mi][ni][r]);
      }
    }
}

// ---------------------------------------------------------------------------
// proj/QK GEMM: 128x128 tile, BK=64 per barrier, 2-slot x 2-half dbuf (64KB).
// EPI 0: fp32 C. EPI 2: bf16 C^T [N][M] + fused BN stats.
// ---------------------------------------------------------------------------
template<int EPI>
__global__ __launch_bounds__(256,2) void gemm_bt128(
    const u16* __restrict__ A, long sA,
    const u16* __restrict__ B, long sB, const int zshB,
    void* __restrict__ Cv, long sC,
    const int M, const int N, const int K,
    float* __restrict__ bnstats,
    const int gxl, const int gyl, const int n8l)
{
  int bx, by, bI;
  xcd_map(gxl, gyl, n8l, bx, by, bI);
  const u16* Ab = A + (long)bI*sA;
  const u16* Bb = B + (long)(bI>>zshB)*sB;
  const int m0 = bx*128, n0 = by*128;
  __shared__ __align__(16) u16 As[16384];   // [2 slot][2 half][128][32]
  __shared__ __align__(16) u16 Bs[16384];
  const int t = threadIdx.x, lane = t & 63, wv = t >> 6;
  const int wm = (wv>>1)*64, wn = (wv&1)*64;
  const int fr = lane & 15, fo = lane >> 4;
  f32x4 acc[4][4] = {};
  const int c0 = wv*128 + lane, c1 = c0 + 64;
  const u16* Ag0 = Ab + (long)(m0 + (c0>>2))*K + (c0&3)*8;
  const u16* Ag1 = Ab + (long)(m0 + (c1>>2))*K + (c1&3)*8;
  const u16* Bg0 = Bb + (long)(n0 + (c0>>2))*K + (c0&3)*8;
  const u16* Bg1 = Bb + (long)(n0 + (c1>>2))*K + (c1&3)*8;
#define STAGEH(slot, h, kofs) { \
    u16* a_ = &As[(((slot)*2+(h))<<12) + wv*1024]; \
    u16* b_ = &Bs[(((slot)*2+(h))<<12) + wv*1024]; \
    const int ko_ = (kofs) + 32*(h); \
    gload_lds16(Ag0 + ko_, a_); \
    gload_lds16(Ag1 + ko_, a_ + 512); \
    gload_lds16(Bg0 + ko_, b_); \
    gload_lds16(Bg1 + ko_, b_ + 512); }
  STAGEH(0, 0, 0)
  STAGEH(0, 1, 0)
  const int nk = K >> 6;
  int cur = 0;
  for (int ki = 0; ki < nk; ++ki){
    __syncthreads();
    if (ki + 1 < nk){
      const int k0 = (ki + 1) << 6;
      STAGEH(cur^1, 0, k0)
      STAGEH(cur^1, 1, k0)
    }
    #pragma unroll
    for (int h = 0; h < 2; ++h){
      const int ro = ((cur*2 + h) << 12);
      bf16x8 af[4], bfv[4];
      #pragma unroll
      for (int i = 0; i < 4; ++i){
        af[i]  = *(const bf16x8*)&As[ro + (wm + i*16 + fr)*32 + fo*8];
        bfv[i] = *(const bf16x8*)&Bs[ro + (wn + i*16 + fr)*32 + fo*8];
      }
      __builtin_amdgcn_s_setprio(1);
      #pragma unroll
      for (int mi = 0; mi < 4; ++mi)
        #pragma unroll
        for (int ni = 0; ni < 4; ++ni)
          acc[mi][ni] = __builtin_amdgcn_mfma_f32_16x16x32_bf16(af[mi], bfv[ni], acc[mi][ni], 0, 0, 0);
      __builtin_amdgcn_s_setprio(0);
    }
    cur ^= 1;
  }
#undef STAGEH
  if (EPI == 0){
    float* Cf = (float*)Cv + (long)bI*sC;
    #pragma unroll
    for (int mi = 0; mi < 4; ++mi)
      #pragma unroll
      for (int ni = 0; ni < 4; ++ni){
        const int col = n0 + wn + ni*16 + fr;
        #pragma unroll
        for (int r = 0; r < 4; ++r){
          const int row = m0 + wm + mi*16 + fo*4 + r;
          Cf[(long)row*N + col] = acc[mi][ni][r];
        }
      }
  } else {
    // bf16 C^T [N][M] + fused BN stats
    u16* Cb = (u16*)Cv + (long)bI*sC;
    #pragma unroll
    for (int mi = 0; mi < 4; ++mi)
      #pragma unroll
      for (int ni = 0; ni < 4; ++ni){
        const int col = n0 + wn + ni*16 + fr;
        const int row0 = m0 + wm + mi*16 + fo*4;
        u16x4 o;
        #pragma unroll
        for (int r = 0; r < 4; ++r) o[r] = f2bf(acc[mi][ni][r]);
        *(u16x4*)&Cb[(long)col*M + row0] = o;
      }
    const int sel = bI >> 2;
    float* sums = bnstats + sel*2048;
    #pragma unroll
    for (int ni = 0; ni < 4; ++ni){
      float s = 0.f, q = 0.f;
      #pragma unroll
      for (int mi = 0; mi < 4; ++mi)
        #pragma unroll
        for (int r = 0; r < 4; ++r){
          const float v = acc[mi][ni][r];
          s += v; q += v*v;
        }
      s += __shfl_xor(s, 16); s += __shfl_xor(s, 32);
      q += __shfl_xor(q, 16); q += __shfl_xor(q, 32);
      if (fo == 0){
        const int col = n0 + wn + ni*16 + fr;
        atomicAdd(&sums[col], s);
        atomicAdd(&sums[1024 + col], q);
      }
    }
  }
}

// ---------------------------------------------------------------------------
// FUSED ff1+ff2: per 128-px tile, phase1 h1=[128][256] in LDS (never HBM),
// phase2 out = gelu(h1 @ W2^T + b2) + feat. Deletes 256MB of h1 traffic.
// LDS [128][264] bf16 (pad +8: phase-2 frag reads 2 lanes/bank = free).
// (256,2): acc 128 VGPR phase-1 fits the 256-reg budget (no spill).
// ---------------------------------------------------------------------------
__global__ __launch_bounds__(256,2) void ff_fused(
    const u16* __restrict__ X, const u16* __restrict__ W1b,
    const float* __restrict__ B1, const u16* __restrict__ W2b,
    const float* __restrict__ B2, const float* __restrict__ F,
    float* __restrict__ OUT)
{
  __shared__ __align__(16) u16 h1s[128*264];   // 67.5KB
  const int t = threadIdx.x, lane = t & 63, wv = t >> 6;
  const long m0 = (long)blockIdx.x*128;
  const int fr = lane & 15, fo = lane >> 4;

  // ---- phase 1: h1[128][256] = gelu(X[128][64] @ W1b^T + b1) -> LDS ----
  {
    const int wm = (wv>>1)*64, wn = (wv&1)*128;
    f32x4 acc[4][8] = {};
    #pragma unroll
    for (int kc = 0; kc < 2; ++kc){
      bf16x8 af[4], bf[8];
      #pragma unroll
      for (int mi = 0; mi < 4; ++mi)
        af[mi] = *(const bf16x8*)(X + (m0 + wm + mi*16 + fr)*64 + kc*32 + fo*8);
      #pragma unroll
      for (int ni = 0; ni < 8; ++ni)
        bf[ni] = *(const bf16x8*)(W1b + (long)(wn + ni*16 + fr)*64 + kc*32 + fo*8);
      #pragma unroll
      for (int mi = 0; mi < 4; ++mi)
        #pragma unroll
        for (int ni = 0; ni < 8; ++ni)
          acc[mi][ni] = __builtin_amdgcn_mfma_f32_16x16x32_bf16(af[mi], bf[ni], acc[mi][ni], 0, 0, 0);
    }
    #pragma unroll
    for (int ni = 0; ni < 8; ++ni){
      const int col = wn + ni*16 + fr;
      const float bc = B1[col];
      #pragma unroll
      for (int mi = 0; mi < 4; ++mi){
        const int row0 = wm + mi*16 + fo*4;
        #pragma unroll
        for (int r = 0; r < 4; ++r)
          h1s[(row0 + r)*264 + col] = f2bf(gelu_f(acc[mi][ni][r] + bc));
      }
    }
  }
  __syncthreads();

  // ---- phase 2: out[128][64] = gelu(h1 @ W2b^T + b2) + feat (NCHW fp32) ----
  {
    const int wm2 = wv*32;
    f32x4 acc2[2][4] = {};
    for (int k0 = 0; k0 < 256; k0 += 32){
      bf16x8 af2[2], bf2[4];
      #pragma unroll
      for (int mi = 0; mi < 2; ++mi)
        af2[mi] = *(const bf16x8*)&h1s[(wm2 + mi*16 + fr)*264 + k0 + fo*8];
      #pragma unroll
      for (int ni = 0; ni < 4; ++ni)
        bf2[ni] = *(const bf16x8*)(W2b + (long)(ni*16 + fr)*256 + k0 + fo*8);
      #pragma unroll
      for (int mi = 0; mi < 2; ++mi)
        #pragma unroll
        for (int ni = 0; ni < 4; ++ni)
          acc2[mi][ni] = __builtin_amdgcn_mfma_f32_16x16x32_bf16(af2[mi], bf2[ni], acc2[mi][ni], 0, 0, 0);
    }
    #pragma unroll
    for (int ni = 0; ni < 4; ++ni){
      const int c = ni*16 + fr;
      const float bc = B2[c];
      #pragma unroll
      for (int mi = 0; mi < 2; ++mi){
        const long p = m0 + wm2 + mi*16 + fo*4;
        const int b = (int)(p >> 16), pp = (int)(p & 65535);
        const long idx = ((long)(b*64 + c))*65536 + pp;
        const f4 fres = *(const f4*)&F[idx];
        f4 o;
        #pragma unroll
        for (int r = 0; r < 4; ++r) o[r] = gelu_f(acc2[mi][ni][r] + bc) + fres[r];
        *(f4*)&OUT[idx] = o;
      }
    }
  }
}

// ---------------------------------------------------------------------------
__global__ __launch_bounds__(256) void cvt_w(
    const float* __restrict__ Wq, const float* __restrict__ Wk,
    u16* __restrict__ Oq, u16* __restrict__ Ok)
{
  const long i = ((long)blockIdx.x*256 + threadIdx.x)*4;
  const float* s = blockIdx.y ? Wk : Wq;
  u16* d = blockIdx.y ? Ok : Oq;
  f4 v = *(const f4*)&s[i];
  u16x4 o; o[0]=f2bf(v[0]); o[1]=f2bf(v[1]); o[2]=f2bf(v[2]); o[3]=f2bf(v[3]);
  *(u16x4*)&d[i] = o;
}

__global__ __launch_bounds__(256) void cvt_ffw(
    const float* __restrict__ W1, const float* __restrict__ W2,
    u16* __restrict__ O1, u16* __restrict__ O2)
{
  const long i = ((long)blockIdx.x*256 + threadIdx.x)*4;
  const float* s = blockIdx.y ? W2 : W1;
  u16* d = blockIdx.y ? O2 : O1;
  f4 v = *(const f4*)&s[i];
  u16x4 o; o[0]=f2bf(v[0]); o[1]=f2bf(v[1]); o[2]=f2bf(v[2]); o[3]=f2bf(v[3]);
  *(u16x4*)&d[i] = o;
}

// ---------------------------------------------------------------------------
// BN finalize (stats from fused GEMM epilogue).
// ---------------------------------------------------------------------------
__global__ void bn_fin2(float* __restrict__ stats,
                        const float* __restrict__ gq, const float* __restrict__ bq,
                        const float* __restrict__ gk, const float* __restrict__ bk)
{
  const int sel = blockIdx.y;
  const int d = blockIdx.x*256 + threadIdx.x;
  if (d >= 1024) return;
  const float* sum   = stats + sel*2048;
  const float* sumsq = sum + 1024;
  const float* g    = sel ? gk : gq;
  const float* beta = sel ? bk : bq;
  const float m  = sum[d]   * (1.f/4096.f);
  const float vv = sumsq[d] * (1.f/4096.f) - m*m;
  const float sc = g[d] * rsqrtf(vv + 1e-5f);
  stats[4096 + sel*2048 + d]        = sc;
  stats[4096 + sel*2048 + 1024 + d] = beta[d] - m*sc;
}

// ---------------------------------------------------------------------------
// BN apply + transpose: QT [z][d=1024][l=1024] bf16 -> Y [z][l][d] bf16.
// ---------------------------------------------------------------------------
__global__ __launch_bounds__(256) void bn_apply_t(
    const u16* __restrict__ QT, const float* __restrict__ stats,
    u16* __restrict__ Y)
{
  __shared__ u16 tl[64][72];
  const int t = threadIdx.x, zi = blockIdx.z;
  const int d0 = blockIdx.x*64, l0 = blockIdx.y*64;
  const int sel = zi >> 2;
  const u16* S = QT + (long)zi*1048576;
  u16* D = Y + (long)zi*1048576;
  const float* scp = stats + 4096 + sel*2048;
  const float* shp = scp + 1024;
  #pragma unroll
  for (int j = 0; j < 2; ++j){
    const int di = (t>>3) + j*32, lo = (t&7)*8;
    const int d = d0 + di;
    const float sc = scp[d], sh = shp[d];
    u16x8 v = *(const u16x8*)(S + (long)d*1024 + l0 + lo);
    u16x8 o;
    #pragma unroll
    for (int e = 0; e < 8; ++e) o[e] = f2bf(bf2f(v[e])*sc + sh);
    *(u16x8*)&tl[di][lo] = o;
  }
  __syncthreads();
  #pragma unroll
  for (int j = 0; j < 2; ++j){
    const int li = (t>>3) + j*32, dof = (t&7)*8;
    u16x8 v;
    #pragma unroll
    for (int e = 0; e < 8; ++e) v[e] = tl[dof+e][li];
    *(u16x8*)(D + (long)(l0+li)*1024 + d0 + dof) = v;
  }
}

__global__ __launch_bounds__(256) void softmax_k(
    const float* __restrict__ S, u16* __restrict__ P)
{
  const long row = blockIdx.x;
  const float* p = S + row*1024;
  const int t = threadIdx.x;
  f4 v = *(const f4*)&p[t*4];
  v *= 0.03125f;
  float mx = fmaxf(fmaxf(v[0],v[1]), fmaxf(v[2],v[3]));
  #pragma unroll
  for (int o = 1; o < 64; o <<= 1) mx = fmaxf(mx, __shfl_xor(mx, o));
  __shared__ float red[4], red2[4];
  if ((t & 63) == 0) red[t>>6] = mx;
  __syncthreads();
  mx = fmaxf(fmaxf(red[0],red[1]), fmaxf(red[2],red[3]));
  f4 e;
  e[0]=__expf(v[0]-mx); e[1]=__expf(v[1]-mx); e[2]=__expf(v[2]-mx); e[3]=__expf(v[3]-mx);
  float sm = e[0]+e[1]+e[2]+e[3];
  #pragma unroll
  for (int o = 1; o < 64; o <<= 1) sm += __shfl_xor(sm, o);
  if ((t & 63) == 0) red2[t>>6] = sm;
  __syncthreads();
  sm = red2[0]+red2[1]+red2[2]+red2[3];
  const float inv = 1.0f/sm;
  u16x4 o4; o4[0]=f2bf(e[0]*inv); o4[1]=f2bf(e[1]*inv); o4[2]=f2bf(e[2]*inv); o4[3]=f2bf(e[3]*inv);
  *(u16x4*)&P[row*1024 + t*4] = o4;
}

// ---------------------------------------------------------------------------
extern "C" void kernel_launch(void* const* d_in, const int* in_sizes, int n_in,
                              void* d_out, int out_size, void* d_ws, size_t ws_size,
                              hipStream_t stream)
{
  const float* feat  = (const float*)d_in[0];
  const float* w_enc = (const float*)d_in[1];
  const float* b_enc = (const float*)d_in[2];
  const float* w_k   = (const float*)d_in[3];
  const float* b_k   = (const float*)d_in[4];
  const float* w_v   = (const float*)d_in[5];
  const float* b_v   = (const float*)d_in[6];
  const float* fcq_w = (const float*)d_in[7];
  // d_in[8] fcq_b, d_in[10] fck_b: cancelled exactly by train-mode BN.
  const float* fck_w = (const float*)d_in[9];
  const float* bnq_g = (const float*)d_in[11];
  const float* bnq_b = (const float*)d_in[12];
  const float* bnk_g = (const float*)d_in[13];
  const float* bnk_b = (const float*)d_in[14];
  const float* ff1w  = (const float*)d_in[15];
  const float* ff1b  = (const float*)d_in[16];
  const float* ff2w  = (const float*)d_in[17];
  const float* ff2b  = (const float*)d_in[18];

  char* ws = (char*)d_ws;
  u16*   Aq      = (u16*)  (ws);                   // [0,32)  MB [B][L][4096] (Ak follows)
  u16*   Ak      = (u16*)  (ws + (32ull<<20));     // [32,64)
  u16*   Vc      = (u16*)  (ws + (64ull<<20));     // [64,96)  [B][4096][L]
  u16*   Wq      = (u16*)  (ws + (96ull<<20));     // [96,104)  (Wk follows)
  u16*   Wk      = (u16*)  (ws + (104ull<<20));    // [104,112)
  u16*   q_bf    = (u16*)  (ws + (112ull<<20));    // [112,120) (k_bf follows)
  u16*   k_bf    = (u16*)  (ws + (120ull<<20));    // [120,128)
  u16*   qk_rawT = (u16*)  (ws + (128ull<<20));    // [128,144) bf16 pre-BN q|k C^T [z][d][l]
  float* scores  = (float*)(ws + (160ull<<20));    // [160,176)
  u16*   attn    = (u16*)  (ws + (176ull<<20));    // [176,184)
  u16*   out_nhwc= (u16*)  (ws + (184ull<<20));    // [184,216) [B][65536][64]
  u16*   NX      = (u16*)  (ws + (128ull<<20));    // [128,160) transient (dead before qk_rawT)
  u16*   Vl      = (u16*)  (ws + (160ull<<20));    // [160,192) transient (dead before scores)
  u16*   Wt2     = (u16*)  (ws + (216ull<<20));    // +221KB
  float* stats   = (float*)(ws + (217ull<<20));    // 32KB
  u16*   W1b     = (u16*)  (ws + (218ull<<20));    // 32KB [256][64] bf16
  u16*   W2b     = (u16*)  (ws + (218ull<<20) + 65536); // 32KB [64][256] bf16

  hipMemsetAsync(stats, 0, 4096*sizeof(float), stream);

  to_nhwc<<<dim3(1024,4), 256, 0, stream>>>(feat, NX);
  wt_prep<<<dim3(432), 256, 0, stream>>>(w_enc, w_k, w_v, Wt2);
  conv_mfma<<<dim3(16,32,4), 512, 0, stream>>>(NX, Wt2, b_enc, b_k, b_v, Aq, Ak, Vl);
  v_tr<<<dim3(64,16,4), 256, 0, stream>>>(Vl, Vc);
  cvt_w<<<dim3(4096,2), 256, 0, stream>>>(fcq_w, fck_w, Wq, Wk);
  cvt_ffw<<<dim3(16,2), 256, 0, stream>>>(ff1w, ff2w, W1b, W2b);

  // merged q+k projections (z 0..3: q, 4..7: k), bf16 C^T + fused BN stats
  // grid (8,8,8) = 512 blocks: gxl=3, gyl=3, n8l=6
  gemm_bt128<2><<<dim3(8,8,8), 256, 0, stream>>>(Aq, 4194304, Wq, 4194304, 2,
                                                 qk_rawT, 1048576, 1024, 1024, 4096, stats,
                                                 3, 3, 6);

  bn_fin2<<<dim3(4,2), 256, 0, stream>>>(stats, bnq_g, bnq_b, bnk_g, bnk_b);
  bn_apply_t<<<dim3(16,16,8), 256, 0, stream>>>(qk_rawT, stats, q_bf);

  // QK: grid (8,8,4) = 256 blocks: gxl=3, gyl=3, n8l=5
  gemm_bt128<0><<<dim3(8,8,4), 256, 0, stream>>>(q_bf, 1048576, k_bf, 1048576, 0,
                                                 scores, 1048576, 1024, 1024, 1024, nullptr,
                                                 3, 3, 5);
  softmax_k<<<dim3(4096), 256, 0, stream>>>(scores, attn);

  // attn@V: grid (8,32,4) = 1024 blocks: gxl=3, gyl=5, n8l=7 (round-11 config)
  gemm_av<<<dim3(8,32,4), 256, 0, stream>>>(attn, 1048576, Vc, 4194304,
                                            out_nhwc, 1024, 4096, 1024,
                                            3, 5, 7);

  // fused ff1+ff2 (h1 never leaves LDS; saves 256MB HBM traffic)
  ff_fused<<<dim3(2048), 256, 0, stream>>>(out_nhwc, W1b, ff1b, W2b, ff2b,
                                           feat, (float*)d_out);
}

// Round 17
// 450.610 us; speedup vs baseline: 1.2097x; 1.0606x over previous
//
#include <hip/hip_runtime.h>

typedef unsigned short u16;
typedef float f4 __attribute__((ext_vector_type(4)));
typedef float f32x4 __attribute__((ext_vector_type(4)));
typedef short bf16x8 __attribute__((ext_vector_type(8)));
typedef u16 u16x8 __attribute__((ext_vector_type(8)));
typedef u16 u16x4 __attribute__((ext_vector_type(4)));

__device__ __forceinline__ u16 f2bf(float f){
  unsigned u = __float_as_uint(f);
  u = (u + 0x7FFFu + ((u>>16)&1u)) >> 16;
  return (u16)u;
}
__device__ __forceinline__ float bf2f(u16 u){
  return __uint_as_float(((unsigned)u)<<16);
}
// tanh-form GELU: max |dev| vs exact erf-GELU ~1e-3 (threshold is 0.108).
__device__ __forceinline__ float gelu_f(float x){
  float y = 1.5957691216057308f*(x + 0.044715f*x*x*x);
  y = fminf(y, 30.0f);
  float t = __expf(y);
  float r = __builtin_amdgcn_rcpf(t + 1.0f);
  return 0.5f*x*(1.0f + (t - 1.0f)*r);
}

// async global->LDS 16B (LDS dest is wave-uniform base + lane*16)
typedef __attribute__((address_space(1))) const unsigned int as1_cuint;
typedef __attribute__((address_space(3))) unsigned int as3_uint;
__device__ __forceinline__ void gload_lds16(const void* g, void* l){
  __builtin_amdgcn_global_load_lds((as1_cuint*)g, (as3_uint*)l, 16, 0, 0);
}

// ---------------------------------------------------------------------------
// feat NCHW fp32 -> NHWC bf16  ([4][256][256][64])
// ---------------------------------------------------------------------------
__global__ __launch_bounds__(256) void to_nhwc(
    const float* __restrict__ F, u16* __restrict__ O)
{
  __shared__ float tile[64][65];
  const int t = threadIdx.x, b = blockIdx.y;
  const long px0 = (long)blockIdx.x*64;
  const float* Fb = F + (long)b*64*65536;
  #pragma unroll
  for (int i = 0; i < 4; ++i){
    const int ch = (t>>4) + i*16;
    const int pxo = (t&15)*4;
    f4 v = *(const f4*)&Fb[(long)ch*65536 + px0 + pxo];
    tile[ch][pxo]=v[0]; tile[ch][pxo+1]=v[1]; tile[ch][pxo+2]=v[2]; tile[ch][pxo+3]=v[3];
  }
  __syncthreads();
  const int px = t & 63, ch0 = (t>>6)*16;
  u16x8 o0, o1;
  #pragma unroll
  for (int j = 0; j < 8; ++j){ o0[j]=f2bf(tile[ch0+j][px]); o1[j]=f2bf(tile[ch0+8+j][px]); }
  u16* Ob = O + ((long)b*65536 + px0 + px)*64 + ch0;
  *(u16x8*)Ob = o0; *(u16x8*)(Ob+8) = o1;
}

// ---------------------------------------------------------------------------
// merged prep: [0,432) wt_prep | [432,8624) cvt_w | [8624,8656) cvt_ffw
// ---------------------------------------------------------------------------
__global__ __launch_bounds__(256) void prep_all(
    const float* __restrict__ we, const float* __restrict__ wk,
    const float* __restrict__ wv, u16* __restrict__ Wt2,
    const float* __restrict__ Wqf, const float* __restrict__ Wkf,
    u16* __restrict__ Oq, u16* __restrict__ Ok,
    const float* __restrict__ W1, const float* __restrict__ W2,
    u16* __restrict__ O1, u16* __restrict__ O2)
{
  const int bb = blockIdx.x, t = threadIdx.x;
  if (bb < 432){
    const int i = bb*256 + t;   // 110592 total
    const int cio = i & 31;
    const int t1 = i >> 5;
    const int n  = t1 % 192;
    const int t2 = t1 / 192;
    const int kc = t2 & 1, p = t2 >> 1;
    const int dy = p/3, dx = p - dy*3;
    const int ci = kc*32 + cio;
    const float* W = (n < 64) ? we : (n < 128) ? wk : wv;
    const int co = n & 63;
    Wt2[i] = f2bf(W[((co*64 + ci)*3 + dy)*3 + dx]);
  } else if (bb < 8624){
    const int b2 = bb - 432;
    const int sel = b2 >> 12;
    const long i = ((long)(b2 & 4095)*256 + t)*4;
    const float* s = sel ? Wkf : Wqf;
    u16* d = sel ? Ok : Oq;
    f4 v = *(const f4*)&s[i];
    u16x4 o; o[0]=f2bf(v[0]); o[1]=f2bf(v[1]); o[2]=f2bf(v[2]); o[3]=f2bf(v[3]);
    *(u16x4*)&d[i] = o;
  } else {
    const int b3 = bb - 8624;
    const int sel = b3 >> 4;
    const long i = ((long)(b3 & 15)*256 + t)*4;
    const float* s = sel ? W2 : W1;
    u16* d = sel ? O2 : O1;
    f4 v = *(const f4*)&s[i];
    u16x4 o; o[0]=f2bf(v[0]); o[1]=f2bf(v[1]); o[2]=f2bf(v[2]); o[3]=f2bf(v[3]);
    *(u16x4*)&d[i] = o;
  }
}

// ---------------------------------------------------------------------------
// MFMA implicit-GEMM conv (512 thr, 2 blocks/CU, two-phase LDS epilogue).
// ---------------------------------------------------------------------------
__global__ __launch_bounds__(512,2) void conv_mfma(
    const u16* __restrict__ X, const u16* __restrict__ Wt2,
    const float* __restrict__ be, const float* __restrict__ bk, const float* __restrict__ bv,
    u16* __restrict__ Aq, u16* __restrict__ Ak, u16* __restrict__ Vl)
{
  __shared__ __align__(16) u16 smem[24576];   // 48KB: halo / epilogue reuse
  const int t = threadIdx.x, lane = t & 63, wvi = t >> 6;
  const int bx = blockIdx.x, by = blockIdx.y, b = blockIdx.z;
  const int x0 = bx*16, y0 = by*8;
  const u16* Xb = X + (long)b*4194304;

  #pragma unroll
  for (int j = 0; j < 3; ++j){
    const int id = t + j*512;
    if (id < 1440){
      const int row = id / 144, rem = id - row*144, col = rem >> 3, ck = rem & 7;
      const int y = y0 - 1 + row, x = x0 - 1 + col;
      int4 v = {0,0,0,0};
      if ((unsigned)y < 256u && (unsigned)x < 256u)
        v = *(const int4*)(Xb + ((long)y*256 + x)*64 + ck*8);
      *(int4*)&smem[((row*18 + col)*8 + (ck ^ (col&7)))*8] = v;
    }
  }
  __syncthreads();

  const int wm4 = (wvi>>2)*4;
  const int wn  = (wvi&3)*48;
  const int fr = lane & 15, fo = lane >> 4;
  f32x4 acc[4][3] = {};

  #pragma unroll
  for (int dy = 0; dy < 3; ++dy)
  #pragma unroll
  for (int dx = 0; dx < 3; ++dx){
    const int p = dy*3 + dx;
    #pragma unroll
    for (int kc = 0; kc < 2; ++kc){
      bf16x8 af[4], bfv[3];
      const u16* wp = Wt2 + ((long)(p*2 + kc)*192 + wn + fr)*32 + fo*8;
      #pragma unroll
      for (int ni = 0; ni < 3; ++ni)
        bfv[ni] = *(const bf16x8*)(wp + ni*16*32);
      #pragma unroll
      for (int mi = 0; mi < 4; ++mi){
        const int row = wm4 + mi + dy;
        const int col = fr + dx;
        af[mi] = *(const bf16x8*)&smem[((row*18 + col)*8 + ((kc*4+fo) ^ (col&7)))*8];
      }
      #pragma unroll
      for (int mi = 0; mi < 4; ++mi)
        #pragma unroll
        for (int ni = 0; ni < 3; ++ni)
          acc[mi][ni] = __builtin_amdgcn_mfma_f32_16x16x32_bf16(af[mi], bfv[ni], acc[mi][ni], 0, 0, 0);
    }
  }
  __syncthreads();

  // phase 1: bias+GELU, frags -> LDS
  const int c0 = fo*4;
  const int lloc = c0 >> 3, kw0 = c0 & 7;
  #pragma unroll
  for (int ni = 0; ni < 3; ++ni){
    const int n = wn + ni*16 + fr;
    const int mat = n >> 6, co = n & 63;
    const float bias = (mat==0) ? be[co] : (mat==1) ? bk[co] : bv[co];
    #pragma unroll
    for (int mi = 0; mi < 4; ++mi){
      const int r = wm4 + mi;
      u16x4 o;
      #pragma unroll
      for (int rg = 0; rg < 4; ++rg) o[rg] = f2bf(gelu_f(acc[mi][ni][rg] + bias));
      const int e = ((mat*2 + lloc)*64 + co)*64 + ((r*8 + kw0) ^ ((co&7)<<3));
      *(u16x4*)&smem[e] = o;
    }
  }
  __syncthreads();

  // phase 2: six contiguous 8KB rows, 16B/lane coalesced
  const int l_lo = by*32 + bx*2;
  const int co_r = t >> 3, sw = (t&7) ^ (co_r&7);
  const int eoff = co_r*64 + sw*8;
  #pragma unroll
  for (int i = 0; i < 6; ++i){
    const int mat = i >> 1, ll = i & 1;
    u16x8 v = *(const u16x8*)&smem[(mat*2 + ll)*4096 + eoff];
    u16* dst = (mat==0 ? Aq : mat==1 ? Ak : Vl)
             + ((long)b*1024 + l_lo + ll)*4096 + t*8;
    *(u16x8*)dst = v;
  }
}

// ---------------------------------------------------------------------------
// V transpose: [b][l=1024][ck=4096] -> [b][ck][l]
// ---------------------------------------------------------------------------
__global__ __launch_bounds__(256) void v_tr(
    const u16* __restrict__ S, u16* __restrict__ D)
{
  __shared__ u16 tl[64][72];
  const int t = threadIdx.x, b = blockIdx.z;
  const int ck0 = blockIdx.x*64, l0 = blockIdx.y*64;
  const u16* Sb = S + (long)b*4194304;
  u16* Db = D + (long)b*4194304;
  #pragma unroll
  for (int j = 0; j < 2; ++j){
    const int li = (t>>3) + j*32, cko = (t&7)*8;
    *(u16x8*)&tl[li][cko] = *(const u16x8*)(Sb + (long)(l0+li)*4096 + ck0 + cko);
  }
  __syncthreads();
  #pragma unroll
  for (int j = 0; j < 2; ++j){
    const int cki = (t>>3) + j*32, lo = (t&7)*8;
    u16x8 v;
    #pragma unroll
    for (int e = 0; e < 8; ++e) v[e] = tl[lo+e][cki];
    *(u16x8*)(Db + (long)(ck0+cki)*1024 + l0 + lo) = v;
  }
}

// ---------------------------------------------------------------------------
// XCD-aware bijective block swizzle (T1, m204).
// ---------------------------------------------------------------------------
__device__ __forceinline__ void xcd_map(int gxl, int gyl, int n8l,
                                        int& bx, int& by, int& bz){
  const int s = blockIdx.x + (blockIdx.y<<gxl) + (blockIdx.z<<(gxl+gyl));
  const int orig = ((s & 7) << n8l) + (s >> 3);
  bx = orig & ((1<<gxl)-1);
  by = (orig >> gxl) & ((1<<gyl)-1);
  bz = orig >> (gxl+gyl);
}

// ---------------------------------------------------------------------------
// attn@V GEMM: 128x128 tile, BK=32 double-buffer, one barrier per K-step,
// XCD swizzle, setprio, NHWC fold. (256,4): 60 arch + 64 acc = 124 <= 128
// -> 4 blocks/CU (was 3). Spill check: WRITE_SIZE must stay ~90-100MB.
// ---------------------------------------------------------------------------
__global__ __launch_bounds__(256,4) void gemm_av(
    const u16* __restrict__ A, long sA,
    const u16* __restrict__ B, long sB,
    void* __restrict__ Cv,
    const int M, const int N, const int K,
    const int gxl, const int gyl, const int n8l)
{
  int bx, by, bI;
  xcd_map(gxl, gyl, n8l, bx, by, bI);
  const u16* Ab = A + (long)bI*sA;
  const u16* Bb = B + (long)bI*sB;
  const int m0 = bx*128, n0 = by*128;
  __shared__ __align__(16) u16 As[8192];
  __shared__ __align__(16) u16 Bs[8192];
  const int t = threadIdx.x, lane = t & 63, wv = t >> 6;
  const int wm = (wv>>1)*64, wn = (wv&1)*64;
  const int fr = lane & 15, fo = lane >> 4;
  f32x4 acc[4][4] = {};
  const int c0 = wv*128 + lane, c1 = c0 + 64;
  const u16* Ag0 = Ab + (long)(m0 + (c0>>2))*K + (c0&3)*8;
  const u16* Ag1 = Ab + (long)(m0 + (c1>>2))*K + (c1&3)*8;
  const u16* Bg0 = Bb + (long)(n0 + (c0>>2))*K + (c0&3)*8;
  const u16* Bg1 = Bb + (long)(n0 + (c1>>2))*K + (c1&3)*8;
  const int lo0 = wv*1024;
  gload_lds16(Ag0, &As[lo0]);
  gload_lds16(Ag1, &As[lo0 + 512]);
  gload_lds16(Bg0, &Bs[lo0]);
  gload_lds16(Bg1, &Bs[lo0 + 512]);
  const int nk = K >> 5;
  int cur = 0;
  for (int ki = 0; ki < nk; ++ki){
    __syncthreads();
    if (ki + 1 < nk){
      const int k0 = (ki + 1) << 5;
      const int so = ((cur^1) << 12) + lo0;
      gload_lds16(Ag0 + k0, &As[so]);
      gload_lds16(Ag1 + k0, &As[so + 512]);
      gload_lds16(Bg0 + k0, &Bs[so]);
      gload_lds16(Bg1 + k0, &Bs[so + 512]);
    }
    const int ro = cur << 12;
    bf16x8 af[4], bfv[4];
    #pragma unroll
    for (int i = 0; i < 4; ++i){
      af[i]  = *(const bf16x8*)&As[ro + (wm + i*16 + fr)*32 + fo*8];
      bfv[i] = *(const bf16x8*)&Bs[ro + (wn + i*16 + fr)*32 + fo*8];
    }
    __builtin_amdgcn_s_setprio(1);
    #pragma unroll
    for (int mi = 0; mi < 4; ++mi)
      #pragma unroll
      for (int ni = 0; ni < 4; ++ni)
        acc[mi][ni] = __builtin_amdgcn_mfma_f32_16x16x32_bf16(af[mi], bfv[ni], acc[mi][ni], 0, 0, 0);
    __builtin_amdgcn_s_setprio(0);
    cur ^= 1;
  }
  // fold to NHWC: row=l=hb*32+wb, col=ck=c*64+kh*8+kw -> O[b][(hb*8+kh)*256+wb*8+kw][c]
  u16* O = (u16*)Cv;
  #pragma unroll
  for (int mi = 0; mi < 4; ++mi)
    #pragma unroll
    for (int ni = 0; ni < 4; ++ni){
      const int col = n0 + wn + ni*16 + fr;
      const int c = col >> 6, khh = (col>>3)&7, kww = col&7;
      #pragma unroll
      for (int r = 0; r < 4; ++r){
        const int row = m0 + wm + mi*16 + fo*4 + r;
        const int hb = row >> 5, wbb = row & 31;
        O[(((long)bI*65536 + (hb*8+khh)*256 + wbb*8 + kww)<<6) + c] = f2bf(acc[mi][ni][r]);
      }
    }
}

// ---------------------------------------------------------------------------
// proj/QK GEMM: 128x128 tile, BK=64 per barrier, 2-slot x 2-half dbuf (64KB).
// EPI 2: bf16 C^T [N][M] + fused BN stats. EPI 3: bf16 C [M][N] (QK scores).
// ---------------------------------------------------------------------------
template<int EPI>
__global__ __launch_bounds__(256,2) void gemm_bt128(
    const u16* __restrict__ A, long sA,
    const u16* __restrict__ B, long sB, const int zshB,
    void* __restrict__ Cv, long sC,
    const int M, const int N, const int K,
    float* __restrict__ bnstats,
    const int gxl, const int gyl, const int n8l)
{
  int bx, by, bI;
  xcd_map(gxl, gyl, n8l, bx, by, bI);
  const u16* Ab = A + (long)bI*sA;
  const u16* Bb = B + (long)(bI>>zshB)*sB;
  const int m0 = bx*128, n0 = by*128;
  __shared__ __align__(16) u16 As[16384];   // [2 slot][2 half][128][32]
  __shared__ __align__(16) u16 Bs[16384];
  const int t = threadIdx.x, lane = t & 63, wv = t >> 6;
  const int wm = (wv>>1)*64, wn = (wv&1)*64;
  const int fr = lane & 15, fo = lane >> 4;
  f32x4 acc[4][4] = {};
  const int c0 = wv*128 + lane, c1 = c0 + 64;
  const u16* Ag0 = Ab + (long)(m0 + (c0>>2))*K + (c0&3)*8;
  const u16* Ag1 = Ab + (long)(m0 + (c1>>2))*K + (c1&3)*8;
  const u16* Bg0 = Bb + (long)(n0 + (c0>>2))*K + (c0&3)*8;
  const u16* Bg1 = Bb + (long)(n0 + (c1>>2))*K + (c1&3)*8;
#define STAGEH(slot, h, kofs) { \
    u16* a_ = &As[(((slot)*2+(h))<<12) + wv*1024]; \
    u16* b_ = &Bs[(((slot)*2+(h))<<12) + wv*1024]; \
    const int ko_ = (kofs) + 32*(h); \
    gload_lds16(Ag0 + ko_, a_); \
    gload_lds16(Ag1 + ko_, a_ + 512); \
    gload_lds16(Bg0 + ko_, b_); \
    gload_lds16(Bg1 + ko_, b_ + 512); }
  STAGEH(0, 0, 0)
  STAGEH(0, 1, 0)
  const int nk = K >> 6;
  int cur = 0;
  for (int ki = 0; ki < nk; ++ki){
    __syncthreads();
    if (ki + 1 < nk){
      const int k0 = (ki + 1) << 6;
      STAGEH(cur^1, 0, k0)
      STAGEH(cur^1, 1, k0)
    }
    #pragma unroll
    for (int h = 0; h < 2; ++h){
      const int ro = ((cur*2 + h) << 12);
      bf16x8 af[4], bfv[4];
      #pragma unroll
      for (int i = 0; i < 4; ++i){
        af[i]  = *(const bf16x8*)&As[ro + (wm + i*16 + fr)*32 + fo*8];
        bfv[i] = *(const bf16x8*)&Bs[ro + (wn + i*16 + fr)*32 + fo*8];
      }
      __builtin_amdgcn_s_setprio(1);
      #pragma unroll
      for (int mi = 0; mi < 4; ++mi)
        #pragma unroll
        for (int ni = 0; ni < 4; ++ni)
          acc[mi][ni] = __builtin_amdgcn_mfma_f32_16x16x32_bf16(af[mi], bfv[ni], acc[mi][ni], 0, 0, 0);
      __builtin_amdgcn_s_setprio(0);
    }
    cur ^= 1;
  }
#undef STAGEH
  if (EPI == 3){
    // bf16 C [M][N] (QK scores, halves softmax read traffic)
    u16* Cb = (u16*)Cv + (long)bI*sC;
    #pragma unroll
    for (int mi = 0; mi < 4; ++mi)
      #pragma unroll
      for (int ni = 0; ni < 4; ++ni){
        const int col = n0 + wn + ni*16 + fr;
        #pragma unroll
        for (int r = 0; r < 4; ++r){
          const int row = m0 + wm + mi*16 + fo*4 + r;
          Cb[(long)row*N + col] = f2bf(acc[mi][ni][r]);
        }
      }
  } else {
    // bf16 C^T [N][M] + fused BN stats
    u16* Cb = (u16*)Cv + (long)bI*sC;
    #pragma unroll
    for (int mi = 0; mi < 4; ++mi)
      #pragma unroll
      for (int ni = 0; ni < 4; ++ni){
        const int col = n0 + wn + ni*16 + fr;
        const int row0 = m0 + wm + mi*16 + fo*4;
        u16x4 o;
        #pragma unroll
        for (int r = 0; r < 4; ++r) o[r] = f2bf(acc[mi][ni][r]);
        *(u16x4*)&Cb[(long)col*M + row0] = o;
      }
    const int sel = bI >> 2;
    float* sums = bnstats + sel*2048;
    #pragma unroll
    for (int ni = 0; ni < 4; ++ni){
      float s = 0.f, q = 0.f;
      #pragma unroll
      for (int mi = 0; mi < 4; ++mi)
        #pragma unroll
        for (int r = 0; r < 4; ++r){
          const float v = acc[mi][ni][r];
          s += v; q += v*v;
        }
      s += __shfl_xor(s, 16); s += __shfl_xor(s, 32);
      q += __shfl_xor(q, 16); q += __shfl_xor(q, 32);
      if (fo == 0){
        const int col = n0 + wn + ni*16 + fr;
        atomicAdd(&sums[col], s);
        atomicAdd(&sums[1024 + col], q);
      }
    }
  }
}

// ---------------------------------------------------------------------------
// FUSED ff1+ff2 (round-16, verified): h1 lives in LDS only.
// ---------------------------------------------------------------------------
__global__ __launch_bounds__(256,2) void ff_fused(
    const u16* __restrict__ X, const u16* __restrict__ W1b,
    const float* __restrict__ B1, const u16* __restrict__ W2b,
    const float* __restrict__ B2, const float* __restrict__ F,
    float* __restrict__ OUT)
{
  __shared__ __align__(16) u16 h1s[128*264];   // 67.5KB
  const int t = threadIdx.x, lane = t & 63, wv = t >> 6;
  const long m0 = (long)blockIdx.x*128;
  const int fr = lane & 15, fo = lane >> 4;

  {
    const int wm = (wv>>1)*64, wn = (wv&1)*128;
    f32x4 acc[4][8] = {};
    #pragma unroll
    for (int kc = 0; kc < 2; ++kc){
      bf16x8 af[4], bf[8];
      #pragma unroll
      for (int mi = 0; mi < 4; ++mi)
        af[mi] = *(const bf16x8*)(X + (m0 + wm + mi*16 + fr)*64 + kc*32 + fo*8);
      #pragma unroll
      for (int ni = 0; ni < 8; ++ni)
        bf[ni] = *(const bf16x8*)(W1b + (long)(wn + ni*16 + fr)*64 + kc*32 + fo*8);
      #pragma unroll
      for (int mi = 0; mi < 4; ++mi)
        #pragma unroll
        for (int ni = 0; ni < 8; ++ni)
          acc[mi][ni] = __builtin_amdgcn_mfma_f32_16x16x32_bf16(af[mi], bf[ni], acc[mi][ni], 0, 0, 0);
    }
    #pragma unroll
    for (int ni = 0; ni < 8; ++ni){
      const int col = wn + ni*16 + fr;
      const float bc = B1[col];
      #pragma unroll
      for (int mi = 0; mi < 4; ++mi){
        const int row0 = wm + mi*16 + fo*4;
        #pragma unroll
        for (int r = 0; r < 4; ++r)
          h1s[(row0 + r)*264 + col] = f2bf(gelu_f(acc[mi][ni][r] + bc));
      }
    }
  }
  __syncthreads();

  {
    const int wm2 = wv*32;
    f32x4 acc2[2][4] = {};
    for (int k0 = 0; k0 < 256; k0 += 32){
      bf16x8 af2[2], bf2[4];
      #pragma unroll
      for (int mi = 0; mi < 2; ++mi)
        af2[mi] = *(const bf16x8*)&h1s[(wm2 + mi*16 + fr)*264 + k0 + fo*8];
      #pragma unroll
      for (int ni = 0; ni < 4; ++ni)
        bf2[ni] = *(const bf16x8*)(W2b + (long)(ni*16 + fr)*256 + k0 + fo*8);
      #pragma unroll
      for (int mi = 0; mi < 2; ++mi)
        #pragma unroll
        for (int ni = 0; ni < 4; ++ni)
          acc2[mi][ni] = __builtin_amdgcn_mfma_f32_16x16x32_bf16(af2[mi], bf2[ni], acc2[mi][ni], 0, 0, 0);
    }
    #pragma unroll
    for (int ni = 0; ni < 4; ++ni){
      const int c = ni*16 + fr;
      const float bc = B2[c];
      #pragma unroll
      for (int mi = 0; mi < 2; ++mi){
        const long p = m0 + wm2 + mi*16 + fo*4;
        const int b = (int)(p >> 16), pp = (int)(p & 65535);
        const long idx = ((long)(b*64 + c))*65536 + pp;
        const f4 fres = *(const f4*)&F[idx];
        f4 o;
        #pragma unroll
        for (int r = 0; r < 4; ++r) o[r] = gelu_f(acc2[mi][ni][r] + bc) + fres[r];
        *(f4*)&OUT[idx] = o;
      }
    }
  }
}

// ---------------------------------------------------------------------------
// BN finalize (stats from fused GEMM epilogue).
// ---------------------------------------------------------------------------
__global__ void bn_fin2(float* __restrict__ stats,
                        const float* __restrict__ gq, const float* __restrict__ bq,
                        const float* __restrict__ gk, const float* __restrict__ bk)
{
  const int sel = blockIdx.y;
  const int d = blockIdx.x*256 + threadIdx.x;
  if (d >= 1024) return;
  const float* sum   = stats + sel*2048;
  const float* sumsq = sum + 1024;
  const float* g    = sel ? gk : gq;
  const float* beta = sel ? bk : bq;
  const float m  = sum[d]   * (1.f/4096.f);
  const float vv = sumsq[d] * (1.f/4096.f) - m*m;
  const float sc = g[d] * rsqrtf(vv + 1e-5f);
  stats[4096 + sel*2048 + d]        = sc;
  stats[4096 + sel*2048 + 1024 + d] = beta[d] - m*sc;
}

// ---------------------------------------------------------------------------
// BN apply + transpose: QT [z][d=1024][l=1024] bf16 -> Y [z][l][d] bf16.
// ---------------------------------------------------------------------------
__global__ __launch_bounds__(256) void bn_apply_t(
    const u16* __restrict__ QT, const float* __restrict__ stats,
    u16* __restrict__ Y)
{
  __shared__ u16 tl[64][72];
  const int t = threadIdx.x, zi = blockIdx.z;
  const int d0 = blockIdx.x*64, l0 = blockIdx.y*64;
  const int sel = zi >> 2;
  const u16* S = QT + (long)zi*1048576;
  u16* D = Y + (long)zi*1048576;
  const float* scp = stats + 4096 + sel*2048;
  const float* shp = scp + 1024;
  #pragma unroll
  for (int j = 0; j < 2; ++j){
    const int di = (t>>3) + j*32, lo = (t&7)*8;
    const int d = d0 + di;
    const float sc = scp[d], sh = shp[d];
    u16x8 v = *(const u16x8*)(S + (long)d*1024 + l0 + lo);
    u16x8 o;
    #pragma unroll
    for (int e = 0; e < 8; ++e) o[e] = f2bf(bf2f(v[e])*sc + sh);
    *(u16x8*)&tl[di][lo] = o;
  }
  __syncthreads();
  #pragma unroll
  for (int j = 0; j < 2; ++j){
    const int li = (t>>3) + j*32, dof = (t&7)*8;
    u16x8 v;
    #pragma unroll
    for (int e = 0; e < 8; ++e) v[e] = tl[dof+e][li];
    *(u16x8*)(D + (long)(l0+li)*1024 + d0 + dof) = v;
  }
}

// ---------------------------------------------------------------------------
// wave-per-row softmax over bf16 scores (1024 elems); no LDS, no barriers.
// ---------------------------------------------------------------------------
__global__ __launch_bounds__(256) void softmax_w(
    const u16* __restrict__ S, u16* __restrict__ P)
{
  const int wv = threadIdx.x >> 6, lane = threadIdx.x & 63;
  const long row = (long)blockIdx.x*4 + wv;
  const u16* p = S + row*1024 + lane*16;
  u16x8 a = *(const u16x8*)p;
  u16x8 b = *(const u16x8*)(p + 8);
  float v[16];
  #pragma unroll
  for (int j = 0; j < 8; ++j){ v[j] = bf2f(a[j])*0.03125f; v[8+j] = bf2f(b[j])*0.03125f; }
  float mx = v[0];
  #pragma unroll
  for (int j = 1; j < 16; ++j) mx = fmaxf(mx, v[j]);
  #pragma unroll
  for (int o = 1; o < 64; o <<= 1) mx = fmaxf(mx, __shfl_xor(mx, o));
  float sm = 0.f;
  #pragma unroll
  for (int j = 0; j < 16; ++j){ v[j] = __expf(v[j] - mx); sm += v[j]; }
  #pragma unroll
  for (int o = 1; o < 64; o <<= 1) sm += __shfl_xor(sm, o);
  const float inv = 1.0f/sm;
  u16x8 oa, ob;
  #pragma unroll
  for (int j = 0; j < 8; ++j){ oa[j] = f2bf(v[j]*inv); ob[j] = f2bf(v[8+j]*inv); }
  u16* q = P + row*1024 + lane*16;
  *(u16x8*)q = oa; *(u16x8*)(q + 8) = ob;
}

// ---------------------------------------------------------------------------
extern "C" void kernel_launch(void* const* d_in, const int* in_sizes, int n_in,
                              void* d_out, int out_size, void* d_ws, size_t ws_size,
                              hipStream_t stream)
{
  const float* feat  = (const float*)d_in[0];
  const float* w_enc = (const float*)d_in[1];
  const float* b_enc = (const float*)d_in[2];
  const float* w_k   = (const float*)d_in[3];
  const float* b_k   = (const float*)d_in[4];
  const float* w_v   = (const float*)d_in[5];
  const float* b_v   = (const float*)d_in[6];
  const float* fcq_w = (const float*)d_in[7];
  // d_in[8] fcq_b, d_in[10] fck_b: cancelled exactly by train-mode BN.
  const float* fck_w = (const float*)d_in[9];
  const float* bnq_g = (const float*)d_in[11];
  const float* bnq_b = (const float*)d_in[12];
  const float* bnk_g = (const float*)d_in[13];
  const float* bnk_b = (const float*)d_in[14];
  const float* ff1w  = (const float*)d_in[15];
  const float* ff1b  = (const float*)d_in[16];
  const float* ff2w  = (const float*)d_in[17];
  const float* ff2b  = (const float*)d_in[18];

  char* ws = (char*)d_ws;
  u16*   Aq      = (u16*)  (ws);                   // [0,32)  MB [B][L][4096] (Ak follows)
  u16*   Ak      = (u16*)  (ws + (32ull<<20));     // [32,64)
  u16*   Vc      = (u16*)  (ws + (64ull<<20));     // [64,96)  [B][4096][L]
  u16*   Wq      = (u16*)  (ws + (96ull<<20));     // [96,104)  (Wk follows)
  u16*   Wk      = (u16*)  (ws + (104ull<<20));    // [104,112)
  u16*   q_bf    = (u16*)  (ws + (112ull<<20));    // [112,120) (k_bf follows)
  u16*   k_bf    = (u16*)  (ws + (120ull<<20));    // [120,128)
  u16*   qk_rawT = (u16*)  (ws + (128ull<<20));    // [128,144) bf16 pre-BN q|k C^T [z][d][l]
  u16*   scores  = (u16*)  (ws + (160ull<<20));    // [160,168) bf16 [z][l][m]
  u16*   attn    = (u16*)  (ws + (176ull<<20));    // [176,184)
  u16*   out_nhwc= (u16*)  (ws + (184ull<<20));    // [184,216) [B][65536][64]
  u16*   NX      = (u16*)  (ws + (128ull<<20));    // [128,160) transient (dead before qk_rawT)
  u16*   Vl      = (u16*)  (ws + (160ull<<20));    // [160,192) transient (dead before scores)
  u16*   Wt2     = (u16*)  (ws + (216ull<<20));    // +221KB
  float* stats   = (float*)(ws + (217ull<<20));    // 32KB
  u16*   W1b     = (u16*)  (ws + (218ull<<20));    // 32KB [256][64] bf16
  u16*   W2b     = (u16*)  (ws + (218ull<<20) + 65536); // 32KB [64][256] bf16

  hipMemsetAsync(stats, 0, 4096*sizeof(float), stream);

  to_nhwc<<<dim3(1024,4), 256, 0, stream>>>(feat, NX);
  prep_all<<<dim3(8656), 256, 0, stream>>>(w_enc, w_k, w_v, Wt2,
                                           fcq_w, fck_w, Wq, Wk,
                                           ff1w, ff2w, W1b, W2b);
  conv_mfma<<<dim3(16,32,4), 512, 0, stream>>>(NX, Wt2, b_enc, b_k, b_v, Aq, Ak, Vl);
  v_tr<<<dim3(64,16,4), 256, 0, stream>>>(Vl, Vc);

  // merged q+k projections (z 0..3: q, 4..7: k), bf16 C^T + fused BN stats
  // grid (8,8,8) = 512 blocks: gxl=3, gyl=3, n8l=6
  gemm_bt128<2><<<dim3(8,8,8), 256, 0, stream>>>(Aq, 4194304, Wq, 4194304, 2,
                                                 qk_rawT, 1048576, 1024, 1024, 4096, stats,
                                                 3, 3, 6);

  bn_fin2<<<dim3(4,2), 256, 0, stream>>>(stats, bnq_g, bnq_b, bnk_g, bnk_b);
  bn_apply_t<<<dim3(16,16,8), 256, 0, stream>>>(qk_rawT, stats, q_bf);

  // QK: grid (8,8,4) = 256 blocks: gxl=3, gyl=3, n8l=5 -> bf16 scores
  gemm_bt128<3><<<dim3(8,8,4), 256, 0, stream>>>(q_bf, 1048576, k_bf, 1048576, 0,
                                                 scores, 1048576, 1024, 1024, 1024, nullptr,
                                                 3, 3, 5);
  softmax_w<<<dim3(1024), 256, 0, stream>>>(scores, attn);

  // attn@V: grid (8,32,4) = 1024 blocks: gxl=3, gyl=5, n8l=7
  gemm_av<<<dim3(8,32,4), 256, 0, stream>>>(attn, 1048576, Vc, 4194304,
                                            out_nhwc, 1024, 4096, 1024,
                                            3, 5, 7);

  // fused ff1+ff2 (h1 never leaves LDS)
  ff_fused<<<dim3(2048), 256, 0, stream>>>(out_nhwc, W1b, ff1b, W2b, ff2b,
                                           feat, (float*)d_out);
}